// Round 2
// baseline (707.562 us; speedup 1.0000x reference)
//
#include <hip/hip_runtime.h>
#include <math.h>

// ---------------------------------------------------------------------------
// GAT network: 3 layers. N=50000 nodes, E=800000 edges, IN=128, H=2, D=128.
// CSR-by-dst once per call; per layer: fp32 tiled GEMM, el/er dots,
// node_alpha (exact segment softmax -> normalized alpha per CSR slot),
// then one-WAVE-per-node weighted aggregation (float4/lane, shfl broadcast,
// no LDS, no barriers, no per-thread exp).
// ---------------------------------------------------------------------------

#define NEG_ATTN 0.2f
#define NEG_ACT  0.01f

// ---------------- CSR build ----------------

__global__ void count_edges(const int* __restrict__ dst, int* __restrict__ counts, int E) {
    int e = blockIdx.x * blockDim.x + threadIdx.x;
    if (e < E) atomicAdd(&counts[dst[e]], 1);
}

// single-block scan: offsets[0]=0, offsets[i+1]=inclusive_prefix(counts,i)
__global__ void scan_offsets(const int* __restrict__ counts, int* __restrict__ offsets, int N) {
    const int PER = 16;
    __shared__ int tmp[1024];
    __shared__ int carry_sh;
    int t = threadIdx.x;
    if (t == 0) { carry_sh = 0; offsets[0] = 0; }
    __syncthreads();
    for (int base = 0; base < N; base += 1024 * PER) {
        int i0 = base + t * PER;
        int loc[PER];
        int sum = 0;
        #pragma unroll
        for (int j = 0; j < PER; ++j) {
            int i = i0 + j;
            int v = (i < N) ? counts[i] : 0;
            sum += v;
            loc[j] = sum;               // inclusive within thread
        }
        tmp[t] = sum;
        __syncthreads();
        for (int off = 1; off < 1024; off <<= 1) {
            int x = (t >= off) ? tmp[t - off] : 0;
            __syncthreads();
            tmp[t] += x;
            __syncthreads();
        }
        int excl = (t == 0) ? 0 : tmp[t - 1];
        int carry = carry_sh;
        #pragma unroll
        for (int j = 0; j < PER; ++j) {
            int i = i0 + j;
            if (i < N) offsets[i + 1] = carry + excl + loc[j];
        }
        __syncthreads();
        if (t == 0) carry_sh = carry + tmp[1023];
        __syncthreads();
    }
}

__global__ void scatter_edges(const int* __restrict__ src, const int* __restrict__ dst,
                              const int* __restrict__ offsets, int* __restrict__ cursor,
                              int* __restrict__ csr_src, int E) {
    int e = blockIdx.x * blockDim.x + threadIdx.x;
    if (e < E) {
        int d = dst[e];
        int pos = offsets[d] + atomicAdd(&cursor[d], 1);
        csr_src[pos] = src[e];
    }
}

// ---------------- fp32 tiled GEMM: C[M,Nw] = A[M,K] @ B[K,Nw] ----------------
// BM=BN=64, BK=32, 256 threads, 4x4 per thread. K % 32 == 0, Nw % 64 == 0.

__global__ __launch_bounds__(256) void gemm_tiled(
    const float* __restrict__ A, const float* __restrict__ B, float* __restrict__ C,
    int M, int K, int Nw)
{
    const int BM = 64, BN = 64, BK = 32;
    __shared__ float As[BM][BK + 4];
    __shared__ float Bs[BK][BN];
    int tid = threadIdx.x;
    int tx = tid & 15, ty = tid >> 4;
    int bm = blockIdx.x * BM;
    int bn = blockIdx.y * BN;

    float acc[4][4] = {};

    int arow = tid >> 3;            // 0..31
    int acol = (tid & 7) * 4;       // 0..28
    int brow = tid >> 4;            // 0..15
    int bcol = (tid & 15) * 4;      // 0..60

    for (int k0 = 0; k0 < K; k0 += BK) {
        #pragma unroll
        for (int r = 0; r < 2; ++r) {
            int row = arow + r * 32;
            int grow = bm + row;
            if (grow >= M) grow = M - 1;     // clamp (store is guarded)
            float4 v = *reinterpret_cast<const float4*>(&A[(size_t)grow * K + k0 + acol]);
            *reinterpret_cast<float4*>(&As[row][acol]) = v;
        }
        #pragma unroll
        for (int r = 0; r < 2; ++r) {
            int row = brow + r * 16;
            float4 v = *reinterpret_cast<const float4*>(&B[(size_t)(k0 + row) * Nw + bn + bcol]);
            *reinterpret_cast<float4*>(&Bs[row][bcol]) = v;
        }
        __syncthreads();
        #pragma unroll
        for (int k = 0; k < BK; k += 4) {
            float4 a[4];
            float4 br[4];
            #pragma unroll
            for (int i = 0; i < 4; ++i) a[i] = *reinterpret_cast<const float4*>(&As[ty * 4 + i][k]);
            #pragma unroll
            for (int kk = 0; kk < 4; ++kk) br[kk] = *reinterpret_cast<const float4*>(&Bs[k + kk][tx * 4]);
            #pragma unroll
            for (int i = 0; i < 4; ++i) {
                float av[4] = {a[i].x, a[i].y, a[i].z, a[i].w};
                #pragma unroll
                for (int kk = 0; kk < 4; ++kk) {
                    acc[i][0] = fmaf(av[kk], br[kk].x, acc[i][0]);
                    acc[i][1] = fmaf(av[kk], br[kk].y, acc[i][1]);
                    acc[i][2] = fmaf(av[kk], br[kk].z, acc[i][2]);
                    acc[i][3] = fmaf(av[kk], br[kk].w, acc[i][3]);
                }
            }
        }
        __syncthreads();
    }

    #pragma unroll
    for (int i = 0; i < 4; ++i) {
        int gm = bm + ty * 4 + i;
        if (gm < M) {
            float4 v = make_float4(acc[i][0], acc[i][1], acc[i][2], acc[i][3]);
            *reinterpret_cast<float4*>(&C[(size_t)gm * Nw + bn + tx * 4]) = v;
        }
    }
}

// ---------------- el/er: per-(node,head) dots with al/ar ----------------

__global__ __launch_bounds__(256) void compute_eler(
    const float* __restrict__ feat, const float* __restrict__ al, const float* __restrict__ ar,
    float* __restrict__ el, float* __restrict__ er, int N)
{
    int wv = threadIdx.x >> 6, lane = threadIdx.x & 63;
    int n = blockIdx.x * 2 + (wv >> 1);
    int h = wv & 1;
    if (n >= N) return;
    const float* f  = feat + (size_t)n * 256 + h * 128;
    const float* ap = al + h * 128;
    const float* rp = ar + h * 128;
    float f0 = f[lane], f1 = f[lane + 64];
    float pl = fmaf(f0, ap[lane], f1 * ap[lane + 64]);
    float pr = fmaf(f0, rp[lane], f1 * rp[lane + 64]);
    #pragma unroll
    for (int off = 32; off; off >>= 1) {
        pl += __shfl_down(pl, off);
        pr += __shfl_down(pr, off);
    }
    if (lane == 0) {
        el[(size_t)n * 2 + h] = pl;
        er[(size_t)n * 2 + h] = pr;
    }
}

// ---------------- node_alpha: exact segment softmax -> normalized alpha ------
// one thread per node, both heads (float2). Pass 1: stash leaky(e), online
// max+sum. Pass 2: alpha = exp(e-m)/s.

__global__ __launch_bounds__(256) void node_alpha(
    const float* __restrict__ el, const float* __restrict__ er,
    const int* __restrict__ offsets, const int* __restrict__ csr_src,
    float* __restrict__ alpha, int N)
{
    int n = blockIdx.x * blockDim.x + threadIdx.x;
    if (n >= N) return;
    int p0 = offsets[n], p1 = offsets[n + 1];
    float2 ern = *reinterpret_cast<const float2*>(er + 2 * (size_t)n);
    float m0 = -__builtin_inff(), m1 = -__builtin_inff();
    float s0 = 0.f, s1 = 0.f;
    for (int p = p0; p < p1; ++p) {
        int sn = csr_src[p];
        float2 e = *reinterpret_cast<const float2*>(el + 2 * (size_t)sn);
        e.x += ern.x; e.y += ern.y;
        e.x = (e.x >= 0.f) ? e.x : NEG_ATTN * e.x;
        e.y = (e.y >= 0.f) ? e.y : NEG_ATTN * e.y;
        *reinterpret_cast<float2*>(alpha + 2 * (size_t)p) = e;   // stash e
        if (e.x > m0) { s0 = s0 * __expf(m0 - e.x) + 1.f; m0 = e.x; }
        else          { s0 += __expf(e.x - m0); }
        if (e.y > m1) { s1 = s1 * __expf(m1 - e.y) + 1.f; m1 = e.y; }
        else          { s1 += __expf(e.y - m1); }
    }
    float i0 = (s0 > 0.f) ? 1.f / s0 : 0.f;
    float i1 = (s1 > 0.f) ? 1.f / s1 : 0.f;
    for (int p = p0; p < p1; ++p) {
        float2 e = *reinterpret_cast<float2*>(alpha + 2 * (size_t)p);
        e.x = __expf(e.x - m0) * i0;
        e.y = __expf(e.y - m1) * i1;
        *reinterpret_cast<float2*>(alpha + 2 * (size_t)p) = e;
    }
}

// ---------------- weighted aggregation: one wave per node -------------------
// lane -> head h = lane>>5, dims d4 = (lane&31)*4 + h*128 (float4 per lane).
// Per 32-edge chunk: lanes hold src ids / alphas in regs, shfl-broadcast.

__global__ __launch_bounds__(256) void gat_aggregate_w(
    const float* __restrict__ feat, const float* __restrict__ alpha,
    const int* __restrict__ offsets, const int* __restrict__ csr_src,
    const float* __restrict__ bias, float* __restrict__ out, int N, int activate)
{
    int wv = threadIdx.x >> 6, lane = threadIdx.x & 63;
    int n = blockIdx.x * 4 + wv;
    if (n >= N) return;
    int hsel = lane >> 5;
    int d4 = (lane & 31) * 4 + hsel * 128;
    size_t laneoff = (size_t)d4 * 4;
    const char* fbase = (const char*)feat + laneoff;
    int p0 = offsets[n], p1 = offsets[n + 1];

    float4 acc = make_float4(0.f, 0.f, 0.f, 0.f);

    for (int base = p0; base < p1; base += 32) {
        int cnt = min(32, p1 - base);
        int src_v = csr_src[base + min(lane & 31, cnt - 1)];
        float a_v  = alpha[(size_t)base * 2 + min(lane, 2 * cnt - 1)];
        int c = 0;
        for (; c + 2 <= cnt; c += 2) {
            int   s0 = __shfl(src_v, c);
            int   s1 = __shfl(src_v, c + 1);
            float a0 = __shfl(a_v, 2 * c + hsel);
            float a1 = __shfl(a_v, 2 * c + 2 + hsel);
            float4 f0 = *reinterpret_cast<const float4*>(fbase + (size_t)s0 * 1024);
            float4 f1 = *reinterpret_cast<const float4*>(fbase + (size_t)s1 * 1024);
            acc.x = fmaf(a0, f0.x, acc.x);
            acc.y = fmaf(a0, f0.y, acc.y);
            acc.z = fmaf(a0, f0.z, acc.z);
            acc.w = fmaf(a0, f0.w, acc.w);
            acc.x = fmaf(a1, f1.x, acc.x);
            acc.y = fmaf(a1, f1.y, acc.y);
            acc.z = fmaf(a1, f1.z, acc.z);
            acc.w = fmaf(a1, f1.w, acc.w);
        }
        if (c < cnt) {
            int   s0 = __shfl(src_v, c);
            float a0 = __shfl(a_v, 2 * c + hsel);
            float4 f0 = *reinterpret_cast<const float4*>(fbase + (size_t)s0 * 1024);
            acc.x = fmaf(a0, f0.x, acc.x);
            acc.y = fmaf(a0, f0.y, acc.y);
            acc.z = fmaf(a0, f0.z, acc.z);
            acc.w = fmaf(a0, f0.w, acc.w);
        }
    }

    float4 b4 = *reinterpret_cast<const float4*>(bias + d4);
    acc.x += b4.x; acc.y += b4.y; acc.z += b4.z; acc.w += b4.w;
    if (activate) {
        acc.x = (acc.x >= 0.f) ? acc.x : NEG_ACT * acc.x;
        acc.y = (acc.y >= 0.f) ? acc.y : NEG_ACT * acc.y;
        acc.z = (acc.z >= 0.f) ? acc.z : NEG_ACT * acc.z;
        acc.w = (acc.w >= 0.f) ? acc.w : NEG_ACT * acc.w;
    }
    *reinterpret_cast<float4*>(out + (size_t)n * 256 + d4) = acc;
}

// ---------------- layer 2: feat2 = h2 @ W2 (K=256), then scalar softmax -----

__global__ __launch_bounds__(256) void gemv2(const float* __restrict__ h2, const float* __restrict__ W2,
                                             float* __restrict__ feat2, int N)
{
    int wv = threadIdx.x >> 6, lane = threadIdx.x & 63;
    int n = blockIdx.x * 4 + wv;
    if (n >= N) return;
    const float* row = h2 + (size_t)n * 256;
    float p = 0.f;
    #pragma unroll
    for (int i = 0; i < 4; ++i) p = fmaf(row[lane + 64 * i], W2[lane + 64 * i], p);
    #pragma unroll
    for (int off = 32; off; off >>= 1) p += __shfl_down(p, off);
    if (lane == 0) feat2[n] = p;
}

__global__ __launch_bounds__(256) void gat_aggregate2(
    const float* __restrict__ feat2, const float* __restrict__ al2, const float* __restrict__ ar2,
    const float* __restrict__ b2, const int* __restrict__ offsets, const int* __restrict__ csr_src,
    float* __restrict__ out, int N)
{
    int n = blockIdx.x * blockDim.x + threadIdx.x;
    if (n >= N) return;
    float alv = al2[0], arv = ar2[0];
    float ern = feat2[n] * arv;
    float m = -__builtin_inff();
    float s = 0.f, acc = 0.f;
    int end = offsets[n + 1];
    for (int p = offsets[n]; p < end; ++p) {
        int sn = csr_src[p];
        float f = feat2[sn];
        float e = fmaf(f, alv, ern);
        e = (e >= 0.f) ? e : NEG_ATTN * e;
        if (e > m) {
            float sc = __expf(m - e);
            s *= sc; acc *= sc; m = e;
        }
        float w = __expf(e - m);
        s += w;
        acc = fmaf(w, f, acc);
    }
    float o = (s > 0.f) ? (acc / s) : 0.f;
    out[n] = o + b2[0];
}

// ---------------------------------------------------------------------------

extern "C" void kernel_launch(void* const* d_in, const int* in_sizes, int n_in,
                              void* d_out, int out_size, void* d_ws, size_t ws_size,
                              hipStream_t stream)
{
    const float* features = (const float*)d_in[0];
    const int*   src      = (const int*)d_in[1];
    const int*   dst      = (const int*)d_in[2];
    const float* W0  = (const float*)d_in[3];
    const float* al0 = (const float*)d_in[4];
    const float* ar0 = (const float*)d_in[5];
    const float* b0  = (const float*)d_in[6];
    const float* W1  = (const float*)d_in[7];
    const float* al1 = (const float*)d_in[8];
    const float* ar1 = (const float*)d_in[9];
    const float* b1  = (const float*)d_in[10];
    const float* W2  = (const float*)d_in[11];
    const float* al2 = (const float*)d_in[12];
    const float* ar2 = (const float*)d_in[13];
    const float* b2  = (const float*)d_in[14];

    const int IN = 128, HD = 256;
    const int N = in_sizes[0] / IN;
    const int E = in_sizes[1];

    float* out_final = (float*)d_out;          // [N]
    float* h2        = (float*)d_out + N;      // [N,256] (returned h; also used
                                               // as the layer-0 hidden buffer)

    char* ws = (char*)d_ws;
    size_t off = 0;
    auto alloc = [&](size_t bytes) { void* p = ws + off; off += (bytes + 255) & ~255ULL; return p; };
    float* featA  = (float*)alloc((size_t)N * HD * 4);
    float* el     = (float*)alloc((size_t)N * 2 * 4);
    float* er     = (float*)alloc((size_t)N * 2 * 4);
    float* feat2  = (float*)alloc((size_t)N * 4);
    int*   counts = (int*)alloc((size_t)N * 4);
    int*   cursor = (int*)alloc((size_t)N * 4);
    int*   offs   = (int*)alloc((size_t)(N + 1) * 4);
    int*   csr_src = (int*)alloc((size_t)E * 4);
    float* alpha  = (float*)alloc((size_t)E * 2 * 4);

    hipMemsetAsync(counts, 0, (size_t)N * 4, stream);
    hipMemsetAsync(cursor, 0, (size_t)N * 4, stream);

    count_edges<<<(E + 255) / 256, 256, 0, stream>>>(dst, counts, E);
    scan_offsets<<<1, 1024, 0, stream>>>(counts, offs, N);
    scatter_edges<<<(E + 255) / 256, 256, 0, stream>>>(src, dst, offs, cursor, csr_src, E);

    dim3 gemm_grid((N + 63) / 64, HD / 64);

    // layer 0 (hidden output -> h2 region, reused as layer-1 input)
    gemm_tiled<<<gemm_grid, 256, 0, stream>>>(features, W0, featA, N, IN, HD);
    compute_eler<<<(N + 1) / 2, 256, 0, stream>>>(featA, al0, ar0, el, er, N);
    node_alpha<<<(N + 255) / 256, 256, 0, stream>>>(el, er, offs, csr_src, alpha, N);
    gat_aggregate_w<<<(N + 3) / 4, 256, 0, stream>>>(featA, alpha, offs, csr_src, b0, h2, N, 1);

    // layer 1 (output overwrites h2 after gemm consumed it)
    gemm_tiled<<<gemm_grid, 256, 0, stream>>>(h2, W1, featA, N, HD, HD);
    compute_eler<<<(N + 1) / 2, 256, 0, stream>>>(featA, al1, ar1, el, er, N);
    node_alpha<<<(N + 255) / 256, 256, 0, stream>>>(el, er, offs, csr_src, alpha, N);
    gat_aggregate_w<<<(N + 3) / 4, 256, 0, stream>>>(featA, alpha, offs, csr_src, b1, h2, N, 1);

    // layer 2 (scalar head)
    gemv2<<<(N + 3) / 4, 256, 0, stream>>>(h2, W2, feat2, N);
    gat_aggregate2<<<(N + 255) / 256, 256, 0, stream>>>(feat2, al2, ar2, b2, offs, csr_src, out_final, N);
}

// Round 3
// 646.326 us; speedup vs baseline: 1.0947x; 1.0947x over previous
//
#include <hip/hip_runtime.h>
#include <math.h>

// ---------------------------------------------------------------------------
// GAT network: 3 layers. N=50000 nodes, E=800000 edges, IN=128, H=2, D=128.
// CSR-by-dst once per call; per layer: bf16 split-MFMA GEMM (hi/lo, 3 MFMA,
// ~fp32 accuracy), el/er dots, node_alpha (exact segment softmax -> alpha),
// one-wave-per-node weighted aggregation (float4/lane, shfl broadcast).
// ---------------------------------------------------------------------------

#define NEG_ATTN 0.2f
#define NEG_ACT  0.01f

typedef short bf16x8 __attribute__((ext_vector_type(8)));
typedef float f32x4  __attribute__((ext_vector_type(4)));

// ---------------- CSR build ----------------

__global__ void count_edges(const int* __restrict__ dst, int* __restrict__ counts, int E) {
    int e = blockIdx.x * blockDim.x + threadIdx.x;
    if (e < E) atomicAdd(&counts[dst[e]], 1);
}

__global__ void scan_offsets(const int* __restrict__ counts, int* __restrict__ offsets, int N) {
    const int PER = 16;
    __shared__ int tmp[1024];
    __shared__ int carry_sh;
    int t = threadIdx.x;
    if (t == 0) { carry_sh = 0; offsets[0] = 0; }
    __syncthreads();
    for (int base = 0; base < N; base += 1024 * PER) {
        int i0 = base + t * PER;
        int loc[PER];
        int sum = 0;
        #pragma unroll
        for (int j = 0; j < PER; ++j) {
            int i = i0 + j;
            int v = (i < N) ? counts[i] : 0;
            sum += v;
            loc[j] = sum;
        }
        tmp[t] = sum;
        __syncthreads();
        for (int off = 1; off < 1024; off <<= 1) {
            int x = (t >= off) ? tmp[t - off] : 0;
            __syncthreads();
            tmp[t] += x;
            __syncthreads();
        }
        int excl = (t == 0) ? 0 : tmp[t - 1];
        int carry = carry_sh;
        #pragma unroll
        for (int j = 0; j < PER; ++j) {
            int i = i0 + j;
            if (i < N) offsets[i + 1] = carry + excl + loc[j];
        }
        __syncthreads();
        if (t == 0) carry_sh = carry + tmp[1023];
        __syncthreads();
    }
}

__global__ void scatter_edges(const int* __restrict__ src, const int* __restrict__ dst,
                              const int* __restrict__ offsets, int* __restrict__ cursor,
                              int* __restrict__ csr_src, int E) {
    int e = blockIdx.x * blockDim.x + threadIdx.x;
    if (e < E) {
        int d = dst[e];
        int pos = offsets[d] + atomicAdd(&cursor[d], 1);
        csr_src[pos] = src[e];
    }
}

// ---------------- W pre-transpose + bf16 hi/lo split ------------------------
// W[K][Nw] -> Wt_hi/Wt_lo [Nw][K] (bf16 as ushort bits).

__global__ void transpose_w_bf16(const float* __restrict__ W,
                                 unsigned short* __restrict__ Wt_hi,
                                 unsigned short* __restrict__ Wt_lo, int K, int Nw) {
    int idx = blockIdx.x * blockDim.x + threadIdx.x;
    if (idx >= K * Nw) return;
    int k = idx / Nw, n = idx - k * Nw;
    float x = W[idx];
    unsigned bits = __float_as_uint(x);
    unsigned short hh = (unsigned short)(bits >> 16);
    float hf = __uint_as_float(bits & 0xFFFF0000u);
    float lo = x - hf;
    Wt_hi[(size_t)n * K + k] = hh;
    Wt_lo[(size_t)n * K + k] = (unsigned short)(__float_as_uint(lo) >> 16);
}

// ---------------- bf16 split-MFMA GEMM: C[M,Nw] = A[M,K] @ B[K,Nw] ----------
// BM=BN=64, BK=32, 256 threads = 4 waves (2x2 quadrants, 2x2 16x16 frags ea).
// A fp32 converted to hi/lo during staging; B from pre-split Wt_hi/Wt_lo.
// acc += hi*hi + hi*lo + lo*hi  (error ~2^-17 relative).

__global__ __launch_bounds__(256) void gemm_mfma_split(
    const float* __restrict__ A,
    const unsigned short* __restrict__ Bt_hi, const unsigned short* __restrict__ Bt_lo,
    float* __restrict__ C, int M, int K, int Nw)
{
    const int BM = 64, BK = 32, LDT = 40;   // padded row: 40 ushorts = 80B
    __shared__ unsigned short As_hi[64][LDT], As_lo[64][LDT];
    __shared__ unsigned short Bs_hi[64][LDT], Bs_lo[64][LDT];

    int tid = threadIdx.x, wv = tid >> 6, lane = tid & 63;
    int bm = blockIdx.x * BM, bn = blockIdx.y * 64;
    int wr = wv >> 1, wc = wv & 1;

    f32x4 acc[2][2] = {};

    int srow = tid >> 2;            // 0..63
    int skc  = (tid & 3) * 8;       // 0,8,16,24

    int arow_g = min(bm + srow, M - 1);
    const float* Arow = A + (size_t)arow_g * K;
    const unsigned short* Bh = Bt_hi + (size_t)(bn + srow) * K;
    const unsigned short* Bl = Bt_lo + (size_t)(bn + srow) * K;

    int frow = lane & 15;
    int fkg  = (lane >> 4) * 8;

    for (int k0 = 0; k0 < K; k0 += BK) {
        // --- stage A (fp32 -> hi/lo bf16) ---
        float4 v0 = *reinterpret_cast<const float4*>(&Arow[k0 + skc]);
        float4 v1 = *reinterpret_cast<const float4*>(&Arow[k0 + skc + 4]);
        float xs[8] = {v0.x, v0.y, v0.z, v0.w, v1.x, v1.y, v1.z, v1.w};
        unsigned hp[4], lp[4];
        #pragma unroll
        for (int j = 0; j < 4; ++j) {
            unsigned b0 = __float_as_uint(xs[2*j]);
            unsigned b1 = __float_as_uint(xs[2*j+1]);
            float h0 = __uint_as_float(b0 & 0xFFFF0000u);
            float h1 = __uint_as_float(b1 & 0xFFFF0000u);
            unsigned l0 = __float_as_uint(xs[2*j] - h0) >> 16;
            unsigned l1 = __float_as_uint(xs[2*j+1] - h1) >> 16;
            hp[j] = (b0 >> 16) | (b1 & 0xFFFF0000u);
            lp[j] = l0 | (l1 << 16);
        }
        *reinterpret_cast<uint4*>(&As_hi[srow][skc]) = make_uint4(hp[0], hp[1], hp[2], hp[3]);
        *reinterpret_cast<uint4*>(&As_lo[srow][skc]) = make_uint4(lp[0], lp[1], lp[2], lp[3]);
        // --- stage B (pure 16B copies) ---
        *reinterpret_cast<uint4*>(&Bs_hi[srow][skc]) =
            *reinterpret_cast<const uint4*>(&Bh[k0 + skc]);
        *reinterpret_cast<uint4*>(&Bs_lo[srow][skc]) =
            *reinterpret_cast<const uint4*>(&Bl[k0 + skc]);

        __syncthreads();

        bf16x8 ah[2], al[2], bh[2], bl[2];
        #pragma unroll
        for (int i = 0; i < 2; ++i) {
            int r = wr * 32 + i * 16 + frow;
            ah[i] = *reinterpret_cast<const bf16x8*>(&As_hi[r][fkg]);
            al[i] = *reinterpret_cast<const bf16x8*>(&As_lo[r][fkg]);
        }
        #pragma unroll
        for (int j = 0; j < 2; ++j) {
            int r = wc * 32 + j * 16 + frow;
            bh[j] = *reinterpret_cast<const bf16x8*>(&Bs_hi[r][fkg]);
            bl[j] = *reinterpret_cast<const bf16x8*>(&Bs_lo[r][fkg]);
        }
        #pragma unroll
        for (int i = 0; i < 2; ++i)
            #pragma unroll
            for (int j = 0; j < 2; ++j) {
                acc[i][j] = __builtin_amdgcn_mfma_f32_16x16x32_bf16(ah[i], bh[j], acc[i][j], 0, 0, 0);
                acc[i][j] = __builtin_amdgcn_mfma_f32_16x16x32_bf16(ah[i], bl[j], acc[i][j], 0, 0, 0);
                acc[i][j] = __builtin_amdgcn_mfma_f32_16x16x32_bf16(al[i], bh[j], acc[i][j], 0, 0, 0);
            }

        __syncthreads();
    }

    // C/D layout (m89-verified): col = lane&15, row = (lane>>4)*4 + reg
    #pragma unroll
    for (int i = 0; i < 2; ++i) {
        int row0 = bm + wr * 32 + i * 16 + (lane >> 4) * 4;
        #pragma unroll
        for (int j = 0; j < 2; ++j) {
            int col = bn + wc * 32 + j * 16 + (lane & 15);
            #pragma unroll
            for (int r = 0; r < 4; ++r) {
                int row = row0 + r;
                if (row < M) C[(size_t)row * Nw + col] = acc[i][j][r];
            }
        }
    }
}

// ---------------- el/er: per-(node,head) dots with al/ar ----------------

__global__ __launch_bounds__(256) void compute_eler(
    const float* __restrict__ feat, const float* __restrict__ al, const float* __restrict__ ar,
    float* __restrict__ el, float* __restrict__ er, int N)
{
    int wv = threadIdx.x >> 6, lane = threadIdx.x & 63;
    int n = blockIdx.x * 2 + (wv >> 1);
    int h = wv & 1;
    if (n >= N) return;
    const float* f  = feat + (size_t)n * 256 + h * 128;
    const float* ap = al + h * 128;
    const float* rp = ar + h * 128;
    float f0 = f[lane], f1 = f[lane + 64];
    float pl = fmaf(f0, ap[lane], f1 * ap[lane + 64]);
    float pr = fmaf(f0, rp[lane], f1 * rp[lane + 64]);
    #pragma unroll
    for (int off = 32; off; off >>= 1) {
        pl += __shfl_down(pl, off);
        pr += __shfl_down(pr, off);
    }
    if (lane == 0) {
        el[(size_t)n * 2 + h] = pl;
        er[(size_t)n * 2 + h] = pr;
    }
}

// ---------------- node_alpha: exact segment softmax -> normalized alpha -----
// one thread per node, both heads (float2), 4-edge unroll for gather MLP.

__global__ __launch_bounds__(256) void node_alpha(
    const float* __restrict__ el, const float* __restrict__ er,
    const int* __restrict__ offsets, const int* __restrict__ csr_src,
    float* __restrict__ alpha, int N)
{
    int n = blockIdx.x * blockDim.x + threadIdx.x;
    if (n >= N) return;
    int p0 = offsets[n], p1 = offsets[n + 1];
    float2 ern = *reinterpret_cast<const float2*>(er + 2 * (size_t)n);
    float m0 = -__builtin_inff(), m1 = -__builtin_inff();
    float s0 = 0.f, s1 = 0.f;

    auto proc = [&](float2 e, int p) {
        e.x += ern.x; e.y += ern.y;
        e.x = (e.x >= 0.f) ? e.x : NEG_ATTN * e.x;
        e.y = (e.y >= 0.f) ? e.y : NEG_ATTN * e.y;
        *reinterpret_cast<float2*>(alpha + 2 * (size_t)p) = e;
        if (e.x > m0) { s0 = s0 * __expf(m0 - e.x) + 1.f; m0 = e.x; }
        else          { s0 += __expf(e.x - m0); }
        if (e.y > m1) { s1 = s1 * __expf(m1 - e.y) + 1.f; m1 = e.y; }
        else          { s1 += __expf(e.y - m1); }
    };

    int p = p0;
    for (; p + 4 <= p1; p += 4) {
        int s0i = csr_src[p], s1i = csr_src[p + 1], s2i = csr_src[p + 2], s3i = csr_src[p + 3];
        float2 e0 = *reinterpret_cast<const float2*>(el + 2 * (size_t)s0i);
        float2 e1 = *reinterpret_cast<const float2*>(el + 2 * (size_t)s1i);
        float2 e2 = *reinterpret_cast<const float2*>(el + 2 * (size_t)s2i);
        float2 e3 = *reinterpret_cast<const float2*>(el + 2 * (size_t)s3i);
        proc(e0, p); proc(e1, p + 1); proc(e2, p + 2); proc(e3, p + 3);
    }
    for (; p < p1; ++p) {
        int sn = csr_src[p];
        float2 e = *reinterpret_cast<const float2*>(el + 2 * (size_t)sn);
        proc(e, p);
    }

    float i0 = (s0 > 0.f) ? 1.f / s0 : 0.f;
    float i1 = (s1 > 0.f) ? 1.f / s1 : 0.f;
    for (p = p0; p < p1; ++p) {
        float2 e = *reinterpret_cast<float2*>(alpha + 2 * (size_t)p);
        e.x = __expf(e.x - m0) * i0;
        e.y = __expf(e.y - m1) * i1;
        *reinterpret_cast<float2*>(alpha + 2 * (size_t)p) = e;
    }
}

// ---------------- weighted aggregation: one wave per node -------------------
// lane -> head h = lane>>5, dims d4 = (lane&31)*4 + h*128 (float4 per lane).
// 4-edge unroll: 4 independent gather loads in flight.

__global__ __launch_bounds__(256) void gat_aggregate_w(
    const float* __restrict__ feat, const float* __restrict__ alpha,
    const int* __restrict__ offsets, const int* __restrict__ csr_src,
    const float* __restrict__ bias, float* __restrict__ out, int N, int activate)
{
    int wv = threadIdx.x >> 6, lane = threadIdx.x & 63;
    int n = blockIdx.x * 4 + wv;
    if (n >= N) return;
    int hsel = lane >> 5;
    int d4 = (lane & 31) * 4 + hsel * 128;
    const char* fbase = (const char*)feat + (size_t)d4 * 4;
    int p0 = offsets[n], p1 = offsets[n + 1];

    float4 acc = make_float4(0.f, 0.f, 0.f, 0.f);

    for (int base = p0; base < p1; base += 32) {
        int cnt = min(32, p1 - base);
        int src_v = csr_src[base + min(lane & 31, cnt - 1)];
        float a_v  = alpha[(size_t)base * 2 + min(lane, 2 * cnt - 1)];
        int c = 0;
        for (; c + 4 <= cnt; c += 4) {
            int   s0 = __shfl(src_v, c);
            int   s1 = __shfl(src_v, c + 1);
            int   s2 = __shfl(src_v, c + 2);
            int   s3 = __shfl(src_v, c + 3);
            float a0 = __shfl(a_v, 2 * c + hsel);
            float a1 = __shfl(a_v, 2 * c + 2 + hsel);
            float a2 = __shfl(a_v, 2 * c + 4 + hsel);
            float a3 = __shfl(a_v, 2 * c + 6 + hsel);
            float4 f0 = *reinterpret_cast<const float4*>(fbase + (size_t)s0 * 1024);
            float4 f1 = *reinterpret_cast<const float4*>(fbase + (size_t)s1 * 1024);
            float4 f2 = *reinterpret_cast<const float4*>(fbase + (size_t)s2 * 1024);
            float4 f3 = *reinterpret_cast<const float4*>(fbase + (size_t)s3 * 1024);
            acc.x = fmaf(a0, f0.x, acc.x); acc.y = fmaf(a0, f0.y, acc.y);
            acc.z = fmaf(a0, f0.z, acc.z); acc.w = fmaf(a0, f0.w, acc.w);
            acc.x = fmaf(a1, f1.x, acc.x); acc.y = fmaf(a1, f1.y, acc.y);
            acc.z = fmaf(a1, f1.z, acc.z); acc.w = fmaf(a1, f1.w, acc.w);
            acc.x = fmaf(a2, f2.x, acc.x); acc.y = fmaf(a2, f2.y, acc.y);
            acc.z = fmaf(a2, f2.z, acc.z); acc.w = fmaf(a2, f2.w, acc.w);
            acc.x = fmaf(a3, f3.x, acc.x); acc.y = fmaf(a3, f3.y, acc.y);
            acc.z = fmaf(a3, f3.z, acc.z); acc.w = fmaf(a3, f3.w, acc.w);
        }
        for (; c < cnt; ++c) {
            int   s0 = __shfl(src_v, c);
            float a0 = __shfl(a_v, 2 * c + hsel);
            float4 f0 = *reinterpret_cast<const float4*>(fbase + (size_t)s0 * 1024);
            acc.x = fmaf(a0, f0.x, acc.x); acc.y = fmaf(a0, f0.y, acc.y);
            acc.z = fmaf(a0, f0.z, acc.z); acc.w = fmaf(a0, f0.w, acc.w);
        }
    }

    float4 b4 = *reinterpret_cast<const float4*>(bias + d4);
    acc.x += b4.x; acc.y += b4.y; acc.z += b4.z; acc.w += b4.w;
    if (activate) {
        acc.x = (acc.x >= 0.f) ? acc.x : NEG_ACT * acc.x;
        acc.y = (acc.y >= 0.f) ? acc.y : NEG_ACT * acc.y;
        acc.z = (acc.z >= 0.f) ? acc.z : NEG_ACT * acc.z;
        acc.w = (acc.w >= 0.f) ? acc.w : NEG_ACT * acc.w;
    }
    *reinterpret_cast<float4*>(out + (size_t)n * 256 + d4) = acc;
}

// ---------------- layer 2: feat2 = h2 @ W2 (K=256), then scalar softmax -----

__global__ __launch_bounds__(256) void gemv2(const float* __restrict__ h2, const float* __restrict__ W2,
                                             float* __restrict__ feat2, int N)
{
    int wv = threadIdx.x >> 6, lane = threadIdx.x & 63;
    int n = blockIdx.x * 4 + wv;
    if (n >= N) return;
    const float* row = h2 + (size_t)n * 256;
    float p = 0.f;
    #pragma unroll
    for (int i = 0; i < 4; ++i) p = fmaf(row[lane + 64 * i], W2[lane + 64 * i], p);
    #pragma unroll
    for (int off = 32; off; off >>= 1) p += __shfl_down(p, off);
    if (lane == 0) feat2[n] = p;
}

__global__ __launch_bounds__(256) void gat_aggregate2(
    const float* __restrict__ feat2, const float* __restrict__ al2, const float* __restrict__ ar2,
    const float* __restrict__ b2, const int* __restrict__ offsets, const int* __restrict__ csr_src,
    float* __restrict__ out, int N)
{
    int n = blockIdx.x * blockDim.x + threadIdx.x;
    if (n >= N) return;
    float alv = al2[0], arv = ar2[0];
    float ern = feat2[n] * arv;
    float m = -__builtin_inff();
    float s = 0.f, acc = 0.f;
    int end = offsets[n + 1];
    for (int p = offsets[n]; p < end; ++p) {
        int sn = csr_src[p];
        float f = feat2[sn];
        float e = fmaf(f, alv, ern);
        e = (e >= 0.f) ? e : NEG_ATTN * e;
        if (e > m) {
            float sc = __expf(m - e);
            s *= sc; acc *= sc; m = e;
        }
        float w = __expf(e - m);
        s += w;
        acc = fmaf(w, f, acc);
    }
    float o = (s > 0.f) ? (acc / s) : 0.f;
    out[n] = o + b2[0];
}

// ---------------------------------------------------------------------------

extern "C" void kernel_launch(void* const* d_in, const int* in_sizes, int n_in,
                              void* d_out, int out_size, void* d_ws, size_t ws_size,
                              hipStream_t stream)
{
    const float* features = (const float*)d_in[0];
    const int*   src      = (const int*)d_in[1];
    const int*   dst      = (const int*)d_in[2];
    const float* W0  = (const float*)d_in[3];
    const float* al0 = (const float*)d_in[4];
    const float* ar0 = (const float*)d_in[5];
    const float* b0  = (const float*)d_in[6];
    const float* W1  = (const float*)d_in[7];
    const float* al1 = (const float*)d_in[8];
    const float* ar1 = (const float*)d_in[9];
    const float* b1  = (const float*)d_in[10];
    const float* W2  = (const float*)d_in[11];
    const float* al2 = (const float*)d_in[12];
    const float* ar2 = (const float*)d_in[13];
    const float* b2  = (const float*)d_in[14];

    const int IN = 128, HD = 256;
    const int N = in_sizes[0] / IN;
    const int E = in_sizes[1];

    float* out_final = (float*)d_out;          // [N]
    float* h2        = (float*)d_out + N;      // [N,256] (returned h; also the
                                               // layer-0 hidden buffer)

    char* ws = (char*)d_ws;
    size_t off = 0;
    auto alloc = [&](size_t bytes) { void* p = ws + off; off += (bytes + 255) & ~255ULL; return p; };
    float* featA  = (float*)alloc((size_t)N * HD * 4);
    float* el     = (float*)alloc((size_t)N * 2 * 4);
    float* er     = (float*)alloc((size_t)N * 2 * 4);
    float* feat2  = (float*)alloc((size_t)N * 4);
    int*   counts = (int*)alloc((size_t)N * 4);
    int*   cursor = (int*)alloc((size_t)N * 4);
    int*   offs   = (int*)alloc((size_t)(N + 1) * 4);
    int*   csr_src = (int*)alloc((size_t)E * 4);
    float* alpha  = (float*)alloc((size_t)E * 2 * 4);
    unsigned short* Wt0h = (unsigned short*)alloc((size_t)IN * HD * 2);
    unsigned short* Wt0l = (unsigned short*)alloc((size_t)IN * HD * 2);
    unsigned short* Wt1h = (unsigned short*)alloc((size_t)HD * HD * 2);
    unsigned short* Wt1l = (unsigned short*)alloc((size_t)HD * HD * 2);

    hipMemsetAsync(counts, 0, (size_t)N * 4, stream);
    hipMemsetAsync(cursor, 0, (size_t)N * 4, stream);

    transpose_w_bf16<<<(IN * HD + 255) / 256, 256, 0, stream>>>(W0, Wt0h, Wt0l, IN, HD);
    transpose_w_bf16<<<(HD * HD + 255) / 256, 256, 0, stream>>>(W1, Wt1h, Wt1l, HD, HD);

    count_edges<<<(E + 255) / 256, 256, 0, stream>>>(dst, counts, E);
    scan_offsets<<<1, 1024, 0, stream>>>(counts, offs, N);
    scatter_edges<<<(E + 255) / 256, 256, 0, stream>>>(src, dst, offs, cursor, csr_src, E);

    dim3 gemm_grid((N + 63) / 64, HD / 64);

    // layer 0 (hidden output -> h2 region, reused as layer-1 input)
    gemm_mfma_split<<<gemm_grid, 256, 0, stream>>>(features, Wt0h, Wt0l, featA, N, IN, HD);
    compute_eler<<<(N + 1) / 2, 256, 0, stream>>>(featA, al0, ar0, el, er, N);
    node_alpha<<<(N + 255) / 256, 256, 0, stream>>>(el, er, offs, csr_src, alpha, N);
    gat_aggregate_w<<<(N + 3) / 4, 256, 0, stream>>>(featA, alpha, offs, csr_src, b0, h2, N, 1);

    // layer 1 (output overwrites h2 after gemm consumed it)
    gemm_mfma_split<<<gemm_grid, 256, 0, stream>>>(h2, Wt1h, Wt1l, featA, N, HD, HD);
    compute_eler<<<(N + 1) / 2, 256, 0, stream>>>(featA, al1, ar1, el, er, N);
    node_alpha<<<(N + 255) / 256, 256, 0, stream>>>(el, er, offs, csr_src, alpha, N);
    gat_aggregate_w<<<(N + 3) / 4, 256, 0, stream>>>(featA, alpha, offs, csr_src, b1, h2, N, 1);

    // layer 2 (scalar head)
    gemv2<<<(N + 3) / 4, 256, 0, stream>>>(h2, W2, feat2, N);
    gat_aggregate2<<<(N + 255) / 256, 256, 0, stream>>>(feat2, al2, ar2, b2, offs, csr_src, out_final, N);
}

// Round 4
// 510.737 us; speedup vs baseline: 1.3854x; 1.2655x over previous
//
#include <hip/hip_runtime.h>
#include <hip/hip_fp16.h>
#include <math.h>

// ---------------------------------------------------------------------------
// GAT network: 3 layers. N=50000 nodes, E=800000 edges, IN=128, H=2, D=128.
// CSR-by-dst once per call. Per layer: bf16 split-MFMA GEMM (hi/lo, ~fp32
// accuracy), eler_cvt (el/er dots + fp16 feature copy), then a FUSED
// one-wave-per-node kernel doing exact segment softmax (wave-butterfly
// max/sum, online rescale) + fp16 weighted feature aggregation.
// ---------------------------------------------------------------------------

#define NEG_ATTN 0.2f
#define NEG_ACT  0.01f

typedef short bf16x8 __attribute__((ext_vector_type(8)));
typedef float f32x4  __attribute__((ext_vector_type(4)));

// ---------------- CSR build ----------------

__global__ void count_edges(const int* __restrict__ dst, int* __restrict__ counts, int E) {
    int e = blockIdx.x * blockDim.x + threadIdx.x;
    if (e < E) atomicAdd(&counts[dst[e]], 1);
}

__global__ void scan_offsets(const int* __restrict__ counts, int* __restrict__ offsets, int N) {
    const int PER = 16;
    __shared__ int tmp[1024];
    __shared__ int carry_sh;
    int t = threadIdx.x;
    if (t == 0) { carry_sh = 0; offsets[0] = 0; }
    __syncthreads();
    for (int base = 0; base < N; base += 1024 * PER) {
        int i0 = base + t * PER;
        int loc[PER];
        int sum = 0;
        #pragma unroll
        for (int j = 0; j < PER; ++j) {
            int i = i0 + j;
            int v = (i < N) ? counts[i] : 0;
            sum += v;
            loc[j] = sum;
        }
        tmp[t] = sum;
        __syncthreads();
        for (int off = 1; off < 1024; off <<= 1) {
            int x = (t >= off) ? tmp[t - off] : 0;
            __syncthreads();
            tmp[t] += x;
            __syncthreads();
        }
        int excl = (t == 0) ? 0 : tmp[t - 1];
        int carry = carry_sh;
        #pragma unroll
        for (int j = 0; j < PER; ++j) {
            int i = i0 + j;
            if (i < N) offsets[i + 1] = carry + excl + loc[j];
        }
        __syncthreads();
        if (t == 0) carry_sh = carry + tmp[1023];
        __syncthreads();
    }
}

__global__ void scatter_edges(const int* __restrict__ src, const int* __restrict__ dst,
                              const int* __restrict__ offsets, int* __restrict__ cursor,
                              int* __restrict__ csr_src, int E) {
    int e = blockIdx.x * blockDim.x + threadIdx.x;
    if (e < E) {
        int d = dst[e];
        int pos = offsets[d] + atomicAdd(&cursor[d], 1);
        csr_src[pos] = src[e];
    }
}

// ---------------- W pre-transpose + bf16 hi/lo split ------------------------

__global__ void transpose_w_bf16(const float* __restrict__ W,
                                 unsigned short* __restrict__ Wt_hi,
                                 unsigned short* __restrict__ Wt_lo, int K, int Nw) {
    int idx = blockIdx.x * blockDim.x + threadIdx.x;
    if (idx >= K * Nw) return;
    int k = idx / Nw, n = idx - k * Nw;
    float x = W[idx];
    unsigned bits = __float_as_uint(x);
    unsigned short hh = (unsigned short)(bits >> 16);
    float hf = __uint_as_float(bits & 0xFFFF0000u);
    float lo = x - hf;
    Wt_hi[(size_t)n * K + k] = hh;
    Wt_lo[(size_t)n * K + k] = (unsigned short)(__float_as_uint(lo) >> 16);
}

// ---------------- bf16 split-MFMA GEMM: C[M,Nw] = A[M,K] @ B[K,Nw] ----------

__global__ __launch_bounds__(256) void gemm_mfma_split(
    const float* __restrict__ A,
    const unsigned short* __restrict__ Bt_hi, const unsigned short* __restrict__ Bt_lo,
    float* __restrict__ C, int M, int K, int Nw)
{
    const int BM = 64, BK = 32, LDT = 40;
    __shared__ unsigned short As_hi[64][LDT], As_lo[64][LDT];
    __shared__ unsigned short Bs_hi[64][LDT], Bs_lo[64][LDT];

    int tid = threadIdx.x, wv = tid >> 6, lane = tid & 63;
    int bm = blockIdx.x * BM, bn = blockIdx.y * 64;
    int wr = wv >> 1, wc = wv & 1;

    f32x4 acc[2][2] = {};

    int srow = tid >> 2;
    int skc  = (tid & 3) * 8;

    int arow_g = min(bm + srow, M - 1);
    const float* Arow = A + (size_t)arow_g * K;
    const unsigned short* Bh = Bt_hi + (size_t)(bn + srow) * K;
    const unsigned short* Bl = Bt_lo + (size_t)(bn + srow) * K;

    int frow = lane & 15;
    int fkg  = (lane >> 4) * 8;

    for (int k0 = 0; k0 < K; k0 += BK) {
        float4 v0 = *reinterpret_cast<const float4*>(&Arow[k0 + skc]);
        float4 v1 = *reinterpret_cast<const float4*>(&Arow[k0 + skc + 4]);
        float xs[8] = {v0.x, v0.y, v0.z, v0.w, v1.x, v1.y, v1.z, v1.w};
        unsigned hp[4], lp[4];
        #pragma unroll
        for (int j = 0; j < 4; ++j) {
            unsigned b0 = __float_as_uint(xs[2*j]);
            unsigned b1 = __float_as_uint(xs[2*j+1]);
            float h0 = __uint_as_float(b0 & 0xFFFF0000u);
            float h1 = __uint_as_float(b1 & 0xFFFF0000u);
            unsigned l0 = __float_as_uint(xs[2*j] - h0) >> 16;
            unsigned l1 = __float_as_uint(xs[2*j+1] - h1) >> 16;
            hp[j] = (b0 >> 16) | (b1 & 0xFFFF0000u);
            lp[j] = l0 | (l1 << 16);
        }
        *reinterpret_cast<uint4*>(&As_hi[srow][skc]) = make_uint4(hp[0], hp[1], hp[2], hp[3]);
        *reinterpret_cast<uint4*>(&As_lo[srow][skc]) = make_uint4(lp[0], lp[1], lp[2], lp[3]);
        *reinterpret_cast<uint4*>(&Bs_hi[srow][skc]) =
            *reinterpret_cast<const uint4*>(&Bh[k0 + skc]);
        *reinterpret_cast<uint4*>(&Bs_lo[srow][skc]) =
            *reinterpret_cast<const uint4*>(&Bl[k0 + skc]);

        __syncthreads();

        bf16x8 ah[2], al[2], bh[2], bl[2];
        #pragma unroll
        for (int i = 0; i < 2; ++i) {
            int r = wr * 32 + i * 16 + frow;
            ah[i] = *reinterpret_cast<const bf16x8*>(&As_hi[r][fkg]);
            al[i] = *reinterpret_cast<const bf16x8*>(&As_lo[r][fkg]);
        }
        #pragma unroll
        for (int j = 0; j < 2; ++j) {
            int r = wc * 32 + j * 16 + frow;
            bh[j] = *reinterpret_cast<const bf16x8*>(&Bs_hi[r][fkg]);
            bl[j] = *reinterpret_cast<const bf16x8*>(&Bs_lo[r][fkg]);
        }
        #pragma unroll
        for (int i = 0; i < 2; ++i)
            #pragma unroll
            for (int j = 0; j < 2; ++j) {
                acc[i][j] = __builtin_amdgcn_mfma_f32_16x16x32_bf16(ah[i], bh[j], acc[i][j], 0, 0, 0);
                acc[i][j] = __builtin_amdgcn_mfma_f32_16x16x32_bf16(ah[i], bl[j], acc[i][j], 0, 0, 0);
                acc[i][j] = __builtin_amdgcn_mfma_f32_16x16x32_bf16(al[i], bh[j], acc[i][j], 0, 0, 0);
            }

        __syncthreads();
    }

    #pragma unroll
    for (int i = 0; i < 2; ++i) {
        int row0 = bm + wr * 32 + i * 16 + (lane >> 4) * 4;
        #pragma unroll
        for (int j = 0; j < 2; ++j) {
            int col = bn + wc * 32 + j * 16 + (lane & 15);
            #pragma unroll
            for (int r = 0; r < 4; ++r) {
                int row = row0 + r;
                if (row < M) C[(size_t)row * Nw + col] = acc[i][j][r];
            }
        }
    }
}

// ---------------- eler_cvt: el/er dots + fp16 feature copy ------------------
// one block per node; thread t -> element t of the 256-wide row.

__global__ __launch_bounds__(256) void eler_cvt(
    const float* __restrict__ feat, const float* __restrict__ al, const float* __restrict__ ar,
    float* __restrict__ el, float* __restrict__ er, __half* __restrict__ feat16, int N)
{
    __shared__ float red[8];
    int n = blockIdx.x;
    int t = threadIdx.x;
    float f = feat[(size_t)n * 256 + t];
    feat16[(size_t)n * 256 + t] = __float2half(f);
    int h = t >> 7, d = t & 127;
    float pl = f * al[h * 128 + d];
    float pr = f * ar[h * 128 + d];
    #pragma unroll
    for (int off = 32; off; off >>= 1) {
        pl += __shfl_down(pl, off);
        pr += __shfl_down(pr, off);
    }
    int wv = t >> 6, lane = t & 63;
    if (lane == 0) { red[wv * 2] = pl; red[wv * 2 + 1] = pr; }
    __syncthreads();
    if (t == 0) {
        el[(size_t)n * 2]     = red[0] + red[2];
        er[(size_t)n * 2]     = red[1] + red[3];
    } else if (t == 1) {
        el[(size_t)n * 2 + 1] = red[4] + red[6];
        er[(size_t)n * 2 + 1] = red[5] + red[7];
    }
}

// ---------------- fused softmax + aggregation: one wave per node ------------
// lanes 0-31 own edges of the 32-chunk (upper half duplicates); butterfly
// max/sum within each 32-lane half; online rescale; fp16 feature gather.
// lane -> head hsel = lane>>5, dims d4 = (lane&31)*4 + hsel*128.

__global__ __launch_bounds__(256) void gat_fused_agg(
    const __half* __restrict__ feat16, const float* __restrict__ el, const float* __restrict__ er,
    const int* __restrict__ offsets, const int* __restrict__ csr_src,
    const float* __restrict__ bias, float* __restrict__ out, int N, int activate)
{
    int wv = threadIdx.x >> 6, lane = threadIdx.x & 63;
    int n = blockIdx.x * 4 + wv;
    if (n >= N) return;
    int hsel = lane >> 5;
    int d4 = (lane & 31) * 4 + hsel * 128;
    const char* fbase = (const char*)feat16 + (size_t)d4 * 2;
    int p0 = offsets[n], p1 = offsets[n + 1];

    float2 ern = *reinterpret_cast<const float2*>(er + 2 * (size_t)n);
    const float NEG_INF = -__builtin_inff();
    float m0 = NEG_INF, m1 = NEG_INF, s0 = 0.f, s1 = 0.f;
    float4 acc = make_float4(0.f, 0.f, 0.f, 0.f);

    for (int base = p0; base < p1; base += 32) {
        int cnt = min(32, p1 - base);
        int cl = lane & 31;
        bool active = cl < cnt;
        int src_v = csr_src[base + min(cl, cnt - 1)];
        float ex = NEG_INF, ey = NEG_INF;
        if (active) {
            float2 e2 = *reinterpret_cast<const float2*>(el + 2 * (size_t)src_v);
            ex = e2.x + ern.x; ey = e2.y + ern.y;
            ex = (ex >= 0.f) ? ex : NEG_ATTN * ex;
            ey = (ey >= 0.f) ? ey : NEG_ATTN * ey;
        }
        // chunk max within 32-lane half
        float mc0 = ex, mc1 = ey;
        #pragma unroll
        for (int off = 16; off; off >>= 1) {
            mc0 = fmaxf(mc0, __shfl_xor(mc0, off));
            mc1 = fmaxf(mc1, __shfl_xor(mc1, off));
        }
        float nm0 = fmaxf(m0, mc0), nm1 = fmaxf(m1, mc1);
        float sc0 = __expf(m0 - nm0), sc1 = __expf(m1 - nm1);
        float wx = active ? __expf(ex - nm0) : 0.f;
        float wy = active ? __expf(ey - nm1) : 0.f;
        float sw0 = wx, sw1 = wy;
        #pragma unroll
        for (int off = 16; off; off >>= 1) {
            sw0 += __shfl_xor(sw0, off);
            sw1 += __shfl_xor(sw1, off);
        }
        s0 = s0 * sc0 + sw0;
        s1 = s1 * sc1 + sw1;
        float scH = hsel ? sc1 : sc0;
        acc.x *= scH; acc.y *= scH; acc.z *= scH; acc.w *= scH;
        m0 = nm0; m1 = nm1;

        int c = 0;
        for (; c + 4 <= cnt; c += 4) {
            int   i0 = __shfl(src_v, c);
            int   i1 = __shfl(src_v, c + 1);
            int   i2 = __shfl(src_v, c + 2);
            int   i3 = __shfl(src_v, c + 3);
            float ax0 = __shfl(wx, c),     ay0 = __shfl(wy, c);
            float ax1 = __shfl(wx, c + 1), ay1 = __shfl(wy, c + 1);
            float ax2 = __shfl(wx, c + 2), ay2 = __shfl(wy, c + 2);
            float ax3 = __shfl(wx, c + 3), ay3 = __shfl(wy, c + 3);
            float a0 = hsel ? ay0 : ax0;
            float a1 = hsel ? ay1 : ax1;
            float a2 = hsel ? ay2 : ax2;
            float a3 = hsel ? ay3 : ax3;
            uint2 r0 = *reinterpret_cast<const uint2*>(fbase + (size_t)i0 * 512);
            uint2 r1 = *reinterpret_cast<const uint2*>(fbase + (size_t)i1 * 512);
            uint2 r2 = *reinterpret_cast<const uint2*>(fbase + (size_t)i2 * 512);
            uint2 r3 = *reinterpret_cast<const uint2*>(fbase + (size_t)i3 * 512);
            {
                float2 fa = __half22float2(*reinterpret_cast<const __half2*>(&r0.x));
                float2 fb = __half22float2(*reinterpret_cast<const __half2*>(&r0.y));
                acc.x = fmaf(a0, fa.x, acc.x); acc.y = fmaf(a0, fa.y, acc.y);
                acc.z = fmaf(a0, fb.x, acc.z); acc.w = fmaf(a0, fb.y, acc.w);
            }
            {
                float2 fa = __half22float2(*reinterpret_cast<const __half2*>(&r1.x));
                float2 fb = __half22float2(*reinterpret_cast<const __half2*>(&r1.y));
                acc.x = fmaf(a1, fa.x, acc.x); acc.y = fmaf(a1, fa.y, acc.y);
                acc.z = fmaf(a1, fb.x, acc.z); acc.w = fmaf(a1, fb.y, acc.w);
            }
            {
                float2 fa = __half22float2(*reinterpret_cast<const __half2*>(&r2.x));
                float2 fb = __half22float2(*reinterpret_cast<const __half2*>(&r2.y));
                acc.x = fmaf(a2, fa.x, acc.x); acc.y = fmaf(a2, fa.y, acc.y);
                acc.z = fmaf(a2, fb.x, acc.z); acc.w = fmaf(a2, fb.y, acc.w);
            }
            {
                float2 fa = __half22float2(*reinterpret_cast<const __half2*>(&r3.x));
                float2 fb = __half22float2(*reinterpret_cast<const __half2*>(&r3.y));
                acc.x = fmaf(a3, fa.x, acc.x); acc.y = fmaf(a3, fa.y, acc.y);
                acc.z = fmaf(a3, fb.x, acc.z); acc.w = fmaf(a3, fb.y, acc.w);
            }
        }
        for (; c < cnt; ++c) {
            int   i0 = __shfl(src_v, c);
            float ax0 = __shfl(wx, c), ay0 = __shfl(wy, c);
            float a0 = hsel ? ay0 : ax0;
            uint2 r0 = *reinterpret_cast<const uint2*>(fbase + (size_t)i0 * 512);
            float2 fa = __half22float2(*reinterpret_cast<const __half2*>(&r0.x));
            float2 fb = __half22float2(*reinterpret_cast<const __half2*>(&r0.y));
            acc.x = fmaf(a0, fa.x, acc.x); acc.y = fmaf(a0, fa.y, acc.y);
            acc.z = fmaf(a0, fb.x, acc.z); acc.w = fmaf(a0, fb.y, acc.w);
        }
    }

    float inv0 = (s0 > 0.f) ? 1.f / s0 : 0.f;
    float inv1 = (s1 > 0.f) ? 1.f / s1 : 0.f;
    float inv = hsel ? inv1 : inv0;
    float4 b4 = *reinterpret_cast<const float4*>(bias + d4);
    acc.x = fmaf(acc.x, inv, b4.x);
    acc.y = fmaf(acc.y, inv, b4.y);
    acc.z = fmaf(acc.z, inv, b4.z);
    acc.w = fmaf(acc.w, inv, b4.w);
    if (activate) {
        acc.x = (acc.x >= 0.f) ? acc.x : NEG_ACT * acc.x;
        acc.y = (acc.y >= 0.f) ? acc.y : NEG_ACT * acc.y;
        acc.z = (acc.z >= 0.f) ? acc.z : NEG_ACT * acc.z;
        acc.w = (acc.w >= 0.f) ? acc.w : NEG_ACT * acc.w;
    }
    *reinterpret_cast<float4*>(out + (size_t)n * 256 + d4) = acc;
}

// ---------------- layer 2: feat2 = h2 @ W2 (K=256), then scalar softmax -----

__global__ __launch_bounds__(256) void gemv2(const float* __restrict__ h2, const float* __restrict__ W2,
                                             float* __restrict__ feat2, int N)
{
    int wv = threadIdx.x >> 6, lane = threadIdx.x & 63;
    int n = blockIdx.x * 4 + wv;
    if (n >= N) return;
    const float* row = h2 + (size_t)n * 256;
    float p = 0.f;
    #pragma unroll
    for (int i = 0; i < 4; ++i) p = fmaf(row[lane + 64 * i], W2[lane + 64 * i], p);
    #pragma unroll
    for (int off = 32; off; off >>= 1) p += __shfl_down(p, off);
    if (lane == 0) feat2[n] = p;
}

__global__ __launch_bounds__(256) void gat_aggregate2(
    const float* __restrict__ feat2, const float* __restrict__ al2, const float* __restrict__ ar2,
    const float* __restrict__ b2, const int* __restrict__ offsets, const int* __restrict__ csr_src,
    float* __restrict__ out, int N)
{
    int n = blockIdx.x * blockDim.x + threadIdx.x;
    if (n >= N) return;
    float alv = al2[0], arv = ar2[0];
    float ern = feat2[n] * arv;
    float m = -__builtin_inff();
    float s = 0.f, acc = 0.f;
    int end = offsets[n + 1];
    for (int p = offsets[n]; p < end; ++p) {
        int sn = csr_src[p];
        float f = feat2[sn];
        float e = fmaf(f, alv, ern);
        e = (e >= 0.f) ? e : NEG_ATTN * e;
        if (e > m) {
            float sc = __expf(m - e);
            s *= sc; acc *= sc; m = e;
        }
        float w = __expf(e - m);
        s += w;
        acc = fmaf(w, f, acc);
    }
    float o = (s > 0.f) ? (acc / s) : 0.f;
    out[n] = o + b2[0];
}

// ---------------------------------------------------------------------------

extern "C" void kernel_launch(void* const* d_in, const int* in_sizes, int n_in,
                              void* d_out, int out_size, void* d_ws, size_t ws_size,
                              hipStream_t stream)
{
    const float* features = (const float*)d_in[0];
    const int*   src      = (const int*)d_in[1];
    const int*   dst      = (const int*)d_in[2];
    const float* W0  = (const float*)d_in[3];
    const float* al0 = (const float*)d_in[4];
    const float* ar0 = (const float*)d_in[5];
    const float* b0  = (const float*)d_in[6];
    const float* W1  = (const float*)d_in[7];
    const float* al1 = (const float*)d_in[8];
    const float* ar1 = (const float*)d_in[9];
    const float* b1  = (const float*)d_in[10];
    const float* W2  = (const float*)d_in[11];
    const float* al2 = (const float*)d_in[12];
    const float* ar2 = (const float*)d_in[13];
    const float* b2  = (const float*)d_in[14];

    const int IN = 128, HD = 256;
    const int N = in_sizes[0] / IN;
    const int E = in_sizes[1];

    float* out_final = (float*)d_out;          // [N]
    float* h2        = (float*)d_out + N;      // [N,256] (returned h; also the
                                               // layer-0 hidden buffer)

    char* ws = (char*)d_ws;
    size_t off = 0;
    auto alloc = [&](size_t bytes) { void* p = ws + off; off += (bytes + 255) & ~255ULL; return p; };
    float*  featA  = (float*)alloc((size_t)N * HD * 4);
    __half* featH  = (__half*)alloc((size_t)N * HD * 2);
    float*  el     = (float*)alloc((size_t)N * 2 * 4);
    float*  er     = (float*)alloc((size_t)N * 2 * 4);
    float*  feat2  = (float*)alloc((size_t)N * 4);
    int*    counts = (int*)alloc((size_t)N * 4);
    int*    cursor = (int*)alloc((size_t)N * 4);
    int*    offs   = (int*)alloc((size_t)(N + 1) * 4);
    int*    csr_src = (int*)alloc((size_t)E * 4);
    unsigned short* Wt0h = (unsigned short*)alloc((size_t)IN * HD * 2);
    unsigned short* Wt0l = (unsigned short*)alloc((size_t)IN * HD * 2);
    unsigned short* Wt1h = (unsigned short*)alloc((size_t)HD * HD * 2);
    unsigned short* Wt1l = (unsigned short*)alloc((size_t)HD * HD * 2);

    hipMemsetAsync(counts, 0, (size_t)N * 4, stream);
    hipMemsetAsync(cursor, 0, (size_t)N * 4, stream);

    transpose_w_bf16<<<(IN * HD + 255) / 256, 256, 0, stream>>>(W0, Wt0h, Wt0l, IN, HD);
    transpose_w_bf16<<<(HD * HD + 255) / 256, 256, 0, stream>>>(W1, Wt1h, Wt1l, HD, HD);

    count_edges<<<(E + 255) / 256, 256, 0, stream>>>(dst, counts, E);
    scan_offsets<<<1, 1024, 0, stream>>>(counts, offs, N);
    scatter_edges<<<(E + 255) / 256, 256, 0, stream>>>(src, dst, offs, cursor, csr_src, E);

    dim3 gemm_grid((N + 63) / 64, HD / 64);

    // layer 0 (hidden output -> h2 region, reused as layer-1 input)
    gemm_mfma_split<<<gemm_grid, 256, 0, stream>>>(features, Wt0h, Wt0l, featA, N, IN, HD);
    eler_cvt<<<N, 256, 0, stream>>>(featA, al0, ar0, el, er, featH, N);
    gat_fused_agg<<<(N + 3) / 4, 256, 0, stream>>>(featH, el, er, offs, csr_src, b0, h2, N, 1);

    // layer 1 (output overwrites h2 after gemm consumed it)
    gemm_mfma_split<<<gemm_grid, 256, 0, stream>>>(h2, Wt1h, Wt1l, featA, N, HD, HD);
    eler_cvt<<<N, 256, 0, stream>>>(featA, al1, ar1, el, er, featH, N);
    gat_fused_agg<<<(N + 3) / 4, 256, 0, stream>>>(featH, el, er, offs, csr_src, b1, h2, N, 1);

    // layer 2 (scalar head)
    gemv2<<<(N + 3) / 4, 256, 0, stream>>>(h2, W2, feat2, N);
    gat_aggregate2<<<(N + 255) / 256, 256, 0, stream>>>(feat2, al2, ar2, b2, offs, csr_src, out_final, N);
}

// Round 6
// 473.361 us; speedup vs baseline: 1.4948x; 1.0790x over previous
//
#include <hip/hip_runtime.h>
#include <hip/hip_fp16.h>
#include <math.h>

// ---------------------------------------------------------------------------
// GAT network: 3 layers. N=50000 nodes, E=800000 edges, IN=128, H=2, D=128.
// CSR-by-dst once per call. Per layer:
//   gemm_mfma_fused: bf16 split-MFMA GEMM (hi/lo, ~fp32 accuracy) whose
//     epilogue writes fp16 features directly AND accumulates el/er attention
//     dots via within-wave reduce + atomics (no fp32 feature matrix at all);
//   gat_fused_agg: one-wave-per-node exact segment softmax (butterfly
//     max/sum, online rescale) + fp16 weighted aggregation; layer-1 variant
//     also computes feat2 = h . W2 in the epilogue (fused gemv).
// Final layer: wave-per-node lane-parallel scalar softmax aggregate.
// ---------------------------------------------------------------------------

#define NEG_ATTN 0.2f
#define NEG_ACT  0.01f

typedef short bf16x8 __attribute__((ext_vector_type(8)));
typedef float f32x4  __attribute__((ext_vector_type(4)));

// ---------------- CSR build ----------------

__global__ void count_edges(const int* __restrict__ dst, int* __restrict__ counts, int E) {
    int e = blockIdx.x * blockDim.x + threadIdx.x;
    if (e < E) atomicAdd(&counts[dst[e]], 1);
}

__global__ void scan_offsets(const int* __restrict__ counts, int* __restrict__ offsets, int N) {
    const int PER = 16;
    __shared__ int tmp[1024];
    __shared__ int carry_sh;
    int t = threadIdx.x;
    if (t == 0) { carry_sh = 0; offsets[0] = 0; }
    __syncthreads();
    for (int base = 0; base < N; base += 1024 * PER) {
        int i0 = base + t * PER;
        int loc[PER];
        int sum = 0;
        #pragma unroll
        for (int j = 0; j < PER; ++j) {
            int i = i0 + j;
            int v = (i < N) ? counts[i] : 0;
            sum += v;
            loc[j] = sum;
        }
        tmp[t] = sum;
        __syncthreads();
        for (int off = 1; off < 1024; off <<= 1) {
            int x = (t >= off) ? tmp[t - off] : 0;
            __syncthreads();
            tmp[t] += x;
            __syncthreads();
        }
        int excl = (t == 0) ? 0 : tmp[t - 1];
        int carry = carry_sh;
        #pragma unroll
        for (int j = 0; j < PER; ++j) {
            int i = i0 + j;
            if (i < N) offsets[i + 1] = carry + excl + loc[j];
        }
        __syncthreads();
        if (t == 0) carry_sh = carry + tmp[1023];
        __syncthreads();
    }
}

__global__ void scatter_edges(const int* __restrict__ src, const int* __restrict__ dst,
                              const int* __restrict__ offsets, int* __restrict__ cursor,
                              int* __restrict__ csr_src, int E) {
    int e = blockIdx.x * blockDim.x + threadIdx.x;
    if (e < E) {
        int d = dst[e];
        int pos = offsets[d] + atomicAdd(&cursor[d], 1);
        csr_src[pos] = src[e];
    }
}

// ---------------- W pre-transpose + bf16 hi/lo split ------------------------

__global__ void transpose_w_bf16(const float* __restrict__ W,
                                 unsigned short* __restrict__ Wt_hi,
                                 unsigned short* __restrict__ Wt_lo, int K, int Nw) {
    int idx = blockIdx.x * blockDim.x + threadIdx.x;
    if (idx >= K * Nw) return;
    int k = idx / Nw, n = idx - k * Nw;
    float x = W[idx];
    unsigned bits = __float_as_uint(x);
    unsigned short hh = (unsigned short)(bits >> 16);
    float hf = __uint_as_float(bits & 0xFFFF0000u);
    float lo = x - hf;
    Wt_hi[(size_t)n * K + k] = hh;
    Wt_lo[(size_t)n * K + k] = (unsigned short)(__float_as_uint(lo) >> 16);
}

// ---------------- fused GEMM: featH(fp16) + el/er partial dots --------------
// C = A[M,K] @ B[K,256]; BM=BN=64, BK=32, 4 waves (2x2), 2x2 16x16 frags.
// Epilogue: fp16 store of the C tile; per-row partial el/er dot over this
// block's 64 cols, 16-lane butterfly reduce, atomicAdd into el/er[N][2]
// (must be zeroed beforehand). al/ar passed as flat [256] (= H*D).

__global__ __launch_bounds__(256) void gemm_mfma_fused(
    const float* __restrict__ A,
    const unsigned short* __restrict__ Bt_hi, const unsigned short* __restrict__ Bt_lo,
    const float* __restrict__ alf, const float* __restrict__ arf,
    __half* __restrict__ feat16, float* __restrict__ el, float* __restrict__ er,
    int M, int K)
{
    const int BK = 32, LDT = 40;
    __shared__ unsigned short As_hi[64][LDT], As_lo[64][LDT];
    __shared__ unsigned short Bs_hi[64][LDT], Bs_lo[64][LDT];

    int tid = threadIdx.x, wv = tid >> 6, lane = tid & 63;
    int bm = blockIdx.x * 64, bn = blockIdx.y * 64;
    int wr = wv >> 1, wc = wv & 1;

    f32x4 acc[2][2] = {};

    int srow = tid >> 2;
    int skc  = (tid & 3) * 8;

    int arow_g = min(bm + srow, M - 1);
    const float* Arow = A + (size_t)arow_g * K;
    const unsigned short* Bh = Bt_hi + (size_t)(bn + srow) * K;
    const unsigned short* Bl = Bt_lo + (size_t)(bn + srow) * K;

    int frow = lane & 15;
    int fkg  = (lane >> 4) * 8;

    for (int k0 = 0; k0 < K; k0 += BK) {
        float4 v0 = *reinterpret_cast<const float4*>(&Arow[k0 + skc]);
        float4 v1 = *reinterpret_cast<const float4*>(&Arow[k0 + skc + 4]);
        float xs[8] = {v0.x, v0.y, v0.z, v0.w, v1.x, v1.y, v1.z, v1.w};
        unsigned hp[4], lp[4];
        #pragma unroll
        for (int j = 0; j < 4; ++j) {
            unsigned b0 = __float_as_uint(xs[2*j]);
            unsigned b1 = __float_as_uint(xs[2*j+1]);
            float h0 = __uint_as_float(b0 & 0xFFFF0000u);
            float h1 = __uint_as_float(b1 & 0xFFFF0000u);
            unsigned l0 = __float_as_uint(xs[2*j] - h0) >> 16;
            unsigned l1 = __float_as_uint(xs[2*j+1] - h1) >> 16;
            hp[j] = (b0 >> 16) | (b1 & 0xFFFF0000u);
            lp[j] = l0 | (l1 << 16);
        }
        *reinterpret_cast<uint4*>(&As_hi[srow][skc]) = make_uint4(hp[0], hp[1], hp[2], hp[3]);
        *reinterpret_cast<uint4*>(&As_lo[srow][skc]) = make_uint4(lp[0], lp[1], lp[2], lp[3]);
        *reinterpret_cast<uint4*>(&Bs_hi[srow][skc]) =
            *reinterpret_cast<const uint4*>(&Bh[k0 + skc]);
        *reinterpret_cast<uint4*>(&Bs_lo[srow][skc]) =
            *reinterpret_cast<const uint4*>(&Bl[k0 + skc]);

        __syncthreads();

        bf16x8 ah[2], al_[2], bh[2], bl[2];
        #pragma unroll
        for (int i = 0; i < 2; ++i) {
            int r = wr * 32 + i * 16 + frow;
            ah[i]  = *reinterpret_cast<const bf16x8*>(&As_hi[r][fkg]);
            al_[i] = *reinterpret_cast<const bf16x8*>(&As_lo[r][fkg]);
        }
        #pragma unroll
        for (int j = 0; j < 2; ++j) {
            int r = wc * 32 + j * 16 + frow;
            bh[j] = *reinterpret_cast<const bf16x8*>(&Bs_hi[r][fkg]);
            bl[j] = *reinterpret_cast<const bf16x8*>(&Bs_lo[r][fkg]);
        }
        #pragma unroll
        for (int i = 0; i < 2; ++i)
            #pragma unroll
            for (int j = 0; j < 2; ++j) {
                acc[i][j] = __builtin_amdgcn_mfma_f32_16x16x32_bf16(ah[i],  bh[j], acc[i][j], 0, 0, 0);
                acc[i][j] = __builtin_amdgcn_mfma_f32_16x16x32_bf16(ah[i],  bl[j], acc[i][j], 0, 0, 0);
                acc[i][j] = __builtin_amdgcn_mfma_f32_16x16x32_bf16(al_[i], bh[j], acc[i][j], 0, 0, 0);
            }

        __syncthreads();
    }

    // ---- epilogue: C/D layout col=lane&15, row=(lane>>4)*4+reg ----
    int colbase = bn + wc * 32;
    int c0 = colbase + (lane & 15);
    int c1 = c0 + 16;
    float alw0 = alf[c0], alw1 = alf[c1];
    float arw0 = arf[c0], arw1 = arf[c1];
    int hH = colbase >> 7;             // head of this 32-col group
    int g4 = (lane >> 4) * 4;
    int sub = lane & 15;

    #pragma unroll
    for (int i = 0; i < 2; ++i) {
        int row0 = bm + wr * 32 + i * 16 + g4;
        // fp16 stores
        #pragma unroll
        for (int r = 0; r < 4; ++r) {
            int row = row0 + r;
            if (row < M) {
                feat16[(size_t)row * 256 + c0] = __float2half(acc[i][0][r]);
                feat16[(size_t)row * 256 + c1] = __float2half(acc[i][1][r]);
            }
        }
        // partial el/er dots over this block's cols
        float pel[4], per_[4];
        #pragma unroll
        for (int r = 0; r < 4; ++r) {
            pel[r]  = acc[i][0][r] * alw0 + acc[i][1][r] * alw1;
            per_[r] = acc[i][0][r] * arw0 + acc[i][1][r] * arw1;
        }
        #pragma unroll
        for (int off = 1; off < 16; off <<= 1) {
            #pragma unroll
            for (int r = 0; r < 4; ++r) {
                pel[r]  += __shfl_xor(pel[r], off);
                per_[r] += __shfl_xor(per_[r], off);
            }
        }
        if (sub < 4) {
            int row = row0 + sub;
            float v = (sub == 0) ? pel[0] : (sub == 1) ? pel[1] : (sub == 2) ? pel[2] : pel[3];
            if (row < M) atomicAdd(&el[(size_t)row * 2 + hH], v);
        } else if (sub < 8) {
            int r = sub - 4;
            int row = row0 + r;
            float v = (r == 0) ? per_[0] : (r == 1) ? per_[1] : (r == 2) ? per_[2] : per_[3];
            if (row < M) atomicAdd(&er[(size_t)row * 2 + hH], v);
        }
    }
}

// ---------------- fused softmax + aggregation: one wave per node ------------
// lanes 0-31 own edges of the 32-chunk (upper half duplicates); butterfly
// max/sum within each 32-lane half; online rescale; fp16 feature gather.
// If W2 != nullptr, also emits feat2[n] = dot(out_row, W2) (fused gemv).

__global__ __launch_bounds__(256) void gat_fused_agg(
    const __half* __restrict__ feat16, const float* __restrict__ el, const float* __restrict__ er,
    const int* __restrict__ offsets, const int* __restrict__ csr_src,
    const float* __restrict__ bias, float* __restrict__ out, int N, int activate,
    const float* __restrict__ W2, float* __restrict__ feat2)
{
    int wv = threadIdx.x >> 6, lane = threadIdx.x & 63;
    int n = blockIdx.x * 4 + wv;
    if (n >= N) return;
    int hsel = lane >> 5;
    int d4 = (lane & 31) * 4 + hsel * 128;
    const char* fbase = (const char*)feat16 + (size_t)d4 * 2;
    int p0 = offsets[n], p1 = offsets[n + 1];

    float2 ern = *reinterpret_cast<const float2*>(er + 2 * (size_t)n);
    const float NEG_INF = -__builtin_inff();
    float m0 = NEG_INF, m1 = NEG_INF, s0 = 0.f, s1 = 0.f;
    float4 acc = make_float4(0.f, 0.f, 0.f, 0.f);

    for (int base = p0; base < p1; base += 32) {
        int cnt = min(32, p1 - base);
        int cl = lane & 31;
        bool active = cl < cnt;
        int src_v = csr_src[base + min(cl, cnt - 1)];
        float ex = NEG_INF, ey = NEG_INF;
        if (active) {
            float2 e2 = *reinterpret_cast<const float2*>(el + 2 * (size_t)src_v);
            ex = e2.x + ern.x; ey = e2.y + ern.y;
            ex = (ex >= 0.f) ? ex : NEG_ATTN * ex;
            ey = (ey >= 0.f) ? ey : NEG_ATTN * ey;
        }
        float mc0 = ex, mc1 = ey;
        #pragma unroll
        for (int off = 16; off; off >>= 1) {
            mc0 = fmaxf(mc0, __shfl_xor(mc0, off));
            mc1 = fmaxf(mc1, __shfl_xor(mc1, off));
        }
        float nm0 = fmaxf(m0, mc0), nm1 = fmaxf(m1, mc1);
        float sc0 = __expf(m0 - nm0), sc1 = __expf(m1 - nm1);
        float wx = active ? __expf(ex - nm0) : 0.f;
        float wy = active ? __expf(ey - nm1) : 0.f;
        float sw0 = wx, sw1 = wy;
        #pragma unroll
        for (int off = 16; off; off >>= 1) {
            sw0 += __shfl_xor(sw0, off);
            sw1 += __shfl_xor(sw1, off);
        }
        s0 = s0 * sc0 + sw0;
        s1 = s1 * sc1 + sw1;
        float scH = hsel ? sc1 : sc0;
        acc.x *= scH; acc.y *= scH; acc.z *= scH; acc.w *= scH;
        m0 = nm0; m1 = nm1;

        int c = 0;
        for (; c + 4 <= cnt; c += 4) {
            int   i0 = __shfl(src_v, c);
            int   i1 = __shfl(src_v, c + 1);
            int   i2 = __shfl(src_v, c + 2);
            int   i3 = __shfl(src_v, c + 3);
            float ax0 = __shfl(wx, c),     ay0 = __shfl(wy, c);
            float ax1 = __shfl(wx, c + 1), ay1 = __shfl(wy, c + 1);
            float ax2 = __shfl(wx, c + 2), ay2 = __shfl(wy, c + 2);
            float ax3 = __shfl(wx, c + 3), ay3 = __shfl(wy, c + 3);
            float a0 = hsel ? ay0 : ax0;
            float a1 = hsel ? ay1 : ax1;
            float a2 = hsel ? ay2 : ax2;
            float a3 = hsel ? ay3 : ax3;
            uint2 r0 = *reinterpret_cast<const uint2*>(fbase + (size_t)i0 * 512);
            uint2 r1 = *reinterpret_cast<const uint2*>(fbase + (size_t)i1 * 512);
            uint2 r2 = *reinterpret_cast<const uint2*>(fbase + (size_t)i2 * 512);
            uint2 r3 = *reinterpret_cast<const uint2*>(fbase + (size_t)i3 * 512);
            {
                float2 fa = __half22float2(*reinterpret_cast<const __half2*>(&r0.x));
                float2 fb = __half22float2(*reinterpret_cast<const __half2*>(&r0.y));
                acc.x = fmaf(a0, fa.x, acc.x); acc.y = fmaf(a0, fa.y, acc.y);
                acc.z = fmaf(a0, fb.x, acc.z); acc.w = fmaf(a0, fb.y, acc.w);
            }
            {
                float2 fa = __half22float2(*reinterpret_cast<const __half2*>(&r1.x));
                float2 fb = __half22float2(*reinterpret_cast<const __half2*>(&r1.y));
                acc.x = fmaf(a1, fa.x, acc.x); acc.y = fmaf(a1, fa.y, acc.y);
                acc.z = fmaf(a1, fb.x, acc.z); acc.w = fmaf(a1, fb.y, acc.w);
            }
            {
                float2 fa = __half22float2(*reinterpret_cast<const __half2*>(&r2.x));
                float2 fb = __half22float2(*reinterpret_cast<const __half2*>(&r2.y));
                acc.x = fmaf(a2, fa.x, acc.x); acc.y = fmaf(a2, fa.y, acc.y);
                acc.z = fmaf(a2, fb.x, acc.z); acc.w = fmaf(a2, fb.y, acc.w);
            }
            {
                float2 fa = __half22float2(*reinterpret_cast<const __half2*>(&r3.x));
                float2 fb = __half22float2(*reinterpret_cast<const __half2*>(&r3.y));
                acc.x = fmaf(a3, fa.x, acc.x); acc.y = fmaf(a3, fa.y, acc.y);
                acc.z = fmaf(a3, fb.x, acc.z); acc.w = fmaf(a3, fb.y, acc.w);
            }
        }
        for (; c < cnt; ++c) {
            int   i0 = __shfl(src_v, c);
            float ax0 = __shfl(wx, c), ay0 = __shfl(wy, c);
            float a0 = hsel ? ay0 : ax0;
            uint2 r0 = *reinterpret_cast<const uint2*>(fbase + (size_t)i0 * 512);
            float2 fa = __half22float2(*reinterpret_cast<const __half2*>(&r0.x));
            float2 fb = __half22float2(*reinterpret_cast<const __half2*>(&r0.y));
            acc.x = fmaf(a0, fa.x, acc.x); acc.y = fmaf(a0, fa.y, acc.y);
            acc.z = fmaf(a0, fb.x, acc.z); acc.w = fmaf(a0, fb.y, acc.w);
        }
    }

    float inv0 = (s0 > 0.f) ? 1.f / s0 : 0.f;
    float inv1 = (s1 > 0.f) ? 1.f / s1 : 0.f;
    float inv = hsel ? inv1 : inv0;
    float4 b4 = *reinterpret_cast<const float4*>(bias + d4);
    acc.x = fmaf(acc.x, inv, b4.x);
    acc.y = fmaf(acc.y, inv, b4.y);
    acc.z = fmaf(acc.z, inv, b4.z);
    acc.w = fmaf(acc.w, inv, b4.w);
    if (activate) {
        acc.x = (acc.x >= 0.f) ? acc.x : NEG_ACT * acc.x;
        acc.y = (acc.y >= 0.f) ? acc.y : NEG_ACT * acc.y;
        acc.z = (acc.z >= 0.f) ? acc.z : NEG_ACT * acc.z;
        acc.w = (acc.w >= 0.f) ? acc.w : NEG_ACT * acc.w;
    }
    *reinterpret_cast<float4*>(out + (size_t)n * 256 + d4) = acc;

    if (W2 != nullptr) {           // fused gemv: feat2[n] = dot(row, W2)
        float4 w4 = *reinterpret_cast<const float4*>(W2 + d4);
        float d = acc.x * w4.x + acc.y * w4.y + acc.z * w4.z + acc.w * w4.w;
        #pragma unroll
        for (int off = 32; off; off >>= 1) d += __shfl_xor(d, off);
        if (lane == 0) feat2[n] = d;
    }
}

// ---------------- layer 2: wave-per-node scalar softmax aggregate -----------
// lane-per-edge, butterfly max/sum, online rescale across 64-edge chunks.

__global__ __launch_bounds__(256) void gat_aggregate2_wave(
    const float* __restrict__ feat2, const float* __restrict__ al2, const float* __restrict__ ar2,
    const float* __restrict__ b2, const int* __restrict__ offsets, const int* __restrict__ csr_src,
    float* __restrict__ out, int N)
{
    int wv = threadIdx.x >> 6, lane = threadIdx.x & 63;
    int n = blockIdx.x * 4 + wv;
    if (n >= N) return;
    float alv = al2[0], arv = ar2[0];
    float ern = feat2[n] * arv;
    int p0 = offsets[n], p1 = offsets[n + 1];
    const float NEG_INF = -__builtin_inff();
    float m = NEG_INF, s = 0.f, acc = 0.f;

    for (int base = p0; base < p1; base += 64) {
        bool active = (base + lane) < p1;
        int sn = active ? csr_src[base + lane] : 0;
        float f = active ? feat2[sn] : 0.f;
        float e = NEG_INF;
        if (active) {
            e = fmaf(f, alv, ern);
            e = (e >= 0.f) ? e : NEG_ATTN * e;
        }
        float mc = e;
        #pragma unroll
        for (int off = 32; off; off >>= 1) mc = fmaxf(mc, __shfl_xor(mc, off));
        float nm = fmaxf(m, mc);
        float sc = __expf(m - nm);
        float w = active ? __expf(e - nm) : 0.f;
        s   = s * sc + w;
        acc = acc * sc + w * f;
        m = nm;
    }
    #pragma unroll
    for (int off = 32; off; off >>= 1) {
        s   += __shfl_xor(s, off);
        acc += __shfl_xor(acc, off);
    }
    if (lane == 0) out[n] = ((s > 0.f) ? acc / s : 0.f) + b2[0];
}

// ---------------------------------------------------------------------------

extern "C" void kernel_launch(void* const* d_in, const int* in_sizes, int n_in,
                              void* d_out, int out_size, void* d_ws, size_t ws_size,
                              hipStream_t stream)
{
    const float* features = (const float*)d_in[0];
    const int*   src      = (const int*)d_in[1];
    const int*   dst      = (const int*)d_in[2];
    const float* W0  = (const float*)d_in[3];
    const float* al0 = (const float*)d_in[4];
    const float* ar0 = (const float*)d_in[5];
    const float* b0  = (const float*)d_in[6];
    const float* W1  = (const float*)d_in[7];
    const float* al1 = (const float*)d_in[8];
    const float* ar1 = (const float*)d_in[9];
    const float* b1  = (const float*)d_in[10];
    const float* W2  = (const float*)d_in[11];
    const float* al2 = (const float*)d_in[12];
    const float* ar2 = (const float*)d_in[13];
    const float* b2  = (const float*)d_in[14];

    const int IN = 128, HD = 256;
    const int N = in_sizes[0] / IN;
    const int E = in_sizes[1];

    float* out_final = (float*)d_out;          // [N]
    float* h2        = (float*)d_out + N;      // [N,256] (returned h; also the
                                               // layer-0 hidden buffer)

    char* ws = (char*)d_ws;
    size_t off = 0;
    auto alloc = [&](size_t bytes) { void* p = ws + off; off += (bytes + 255) & ~255ULL; return p; };
    __half* featH  = (__half*)alloc((size_t)N * HD * 2);
    float*  el     = (float*)alloc((size_t)N * 2 * 4);
    float*  er     = (float*)alloc((size_t)N * 2 * 4);
    float*  feat2  = (float*)alloc((size_t)N * 4);
    int*    counts = (int*)alloc((size_t)N * 4);
    int*    cursor = (int*)alloc((size_t)N * 4);
    int*    offs   = (int*)alloc((size_t)(N + 1) * 4);
    int*    csr_src = (int*)alloc((size_t)E * 4);
    unsigned short* Wt0h = (unsigned short*)alloc((size_t)IN * HD * 2);
    unsigned short* Wt0l = (unsigned short*)alloc((size_t)IN * HD * 2);
    unsigned short* Wt1h = (unsigned short*)alloc((size_t)HD * HD * 2);
    unsigned short* Wt1l = (unsigned short*)alloc((size_t)HD * HD * 2);

    hipMemsetAsync(counts, 0, (size_t)N * 4, stream);
    hipMemsetAsync(cursor, 0, (size_t)N * 4, stream);

    transpose_w_bf16<<<(IN * HD + 255) / 256, 256, 0, stream>>>(W0, Wt0h, Wt0l, IN, HD);
    transpose_w_bf16<<<(HD * HD + 255) / 256, 256, 0, stream>>>(W1, Wt1h, Wt1l, HD, HD);

    count_edges<<<(E + 255) / 256, 256, 0, stream>>>(dst, counts, E);
    scan_offsets<<<1, 1024, 0, stream>>>(counts, offs, N);
    scatter_edges<<<(E + 255) / 256, 256, 0, stream>>>(src, dst, offs, cursor, csr_src, E);

    dim3 gemm_grid((N + 63) / 64, HD / 64);

    // layer 0 (fp16 features + el/er straight out of the GEMM)
    hipMemsetAsync(el, 0, (size_t)N * 2 * 4, stream);
    hipMemsetAsync(er, 0, (size_t)N * 2 * 4, stream);
    gemm_mfma_fused<<<gemm_grid, 256, 0, stream>>>(features, Wt0h, Wt0l, al0, ar0,
                                                   featH, el, er, N, IN);
    gat_fused_agg<<<(N + 3) / 4, 256, 0, stream>>>(featH, el, er, offs, csr_src, b0,
                                                   h2, N, 1, nullptr, nullptr);

    // layer 1 (h2 -> featH/el/er; agg writes final h AND feat2 = h.W2)
    hipMemsetAsync(el, 0, (size_t)N * 2 * 4, stream);
    hipMemsetAsync(er, 0, (size_t)N * 2 * 4, stream);
    gemm_mfma_fused<<<gemm_grid, 256, 0, stream>>>(h2, Wt1h, Wt1l, al1, ar1,
                                                   featH, el, er, N, HD);
    gat_fused_agg<<<(N + 3) / 4, 256, 0, stream>>>(featH, el, er, offs, csr_src, b1,
                                                   h2, N, 1, W2, feat2);

    // layer 2 (scalar head, wave-per-node)
    gat_aggregate2_wave<<<(N + 3) / 4, 256, 0, stream>>>(feat2, al2, ar2, b2, offs,
                                                         csr_src, out_final, N);
}

// Round 7
// 434.733 us; speedup vs baseline: 1.6276x; 1.0889x over previous
//
#include <hip/hip_runtime.h>
#include <hip/hip_fp16.h>
#include <math.h>

// ---------------------------------------------------------------------------
// GAT network: 3 layers. N=50000 nodes, E=800000 edges, IN=128, H=2, D=128.
// CSR-by-dst once per call (parallel 3-kernel scan). Per layer:
//   gemm_bf16split: bf16 split-MFMA GEMM with PRE-SPLIT hi/lo A and B in
//     global (pure-copy staging, BK=64); epilogue writes fp16 features and
//     accumulates el/er attention dots (wave reduce + atomics).
//   gat_fused_agg: one-wave-per-node exact segment softmax + fp16 weighted
//     aggregation; layer-0 variant also emits h1 as bf16 hi/lo (next GEMM's
//     A); layer-1 variant computes feat2 = h . W2 (fused gemv).
// Final layer: wave-per-node lane-parallel scalar softmax aggregate.
// ---------------------------------------------------------------------------

#define NEG_ATTN 0.2f
#define NEG_ACT  0.01f

typedef short bf16x8 __attribute__((ext_vector_type(8)));
typedef float f32x4  __attribute__((ext_vector_type(4)));
typedef unsigned short ushort_t;

__device__ inline void bf16split(float x, unsigned short& h, unsigned short& l) {
    unsigned b = __float_as_uint(x);
    h = (unsigned short)(b >> 16);
    float hf = __uint_as_float(b & 0xFFFF0000u);
    l = (unsigned short)(__float_as_uint(x - hf) >> 16);
}

// ---------------- CSR build ----------------

__global__ void count_edges(const int* __restrict__ dst, int* __restrict__ counts, int E) {
    int e = blockIdx.x * blockDim.x + threadIdx.x;
    if (e < E) atomicAdd(&counts[dst[e]], 1);
}

// parallel scan, phase 1: per-block inclusive scan + block sums
__global__ __launch_bounds__(256) void scan_phase1(
    const int* __restrict__ in, int* __restrict__ out1 /* = offsets+1 */,
    int* __restrict__ bsum, int n)
{
    __shared__ int wsum[4];
    int i = blockIdx.x * 256 + threadIdx.x;
    int lane = threadIdx.x & 63, wv = threadIdx.x >> 6;
    int v = (i < n) ? in[i] : 0;
    int x = v;
    #pragma unroll
    for (int off = 1; off < 64; off <<= 1) {
        int y = __shfl_up(x, off);
        if (lane >= off) x += y;
    }
    if (lane == 63) wsum[wv] = x;
    __syncthreads();
    int add = 0;
    for (int w = 0; w < wv; ++w) add += wsum[w];
    x += add;
    if (i < n) out1[i] = x;
    if (threadIdx.x == 255) bsum[blockIdx.x] = x;
}

// phase 2: single-block inclusive scan of block sums (nb <= 256)
__global__ __launch_bounds__(256) void scan_phase2(int* __restrict__ bsum, int nb) {
    __shared__ int wsum[4];
    int t = threadIdx.x;
    int lane = t & 63, wv = t >> 6;
    int x = (t < nb) ? bsum[t] : 0;
    #pragma unroll
    for (int off = 1; off < 64; off <<= 1) {
        int y = __shfl_up(x, off);
        if (lane >= off) x += y;
    }
    if (lane == 63) wsum[wv] = x;
    __syncthreads();
    int add = 0;
    for (int w = 0; w < wv; ++w) add += wsum[w];
    x += add;
    if (t < nb) bsum[t] = x;
}

// phase 3: add block prefixes; set offsets[0] = 0
__global__ __launch_bounds__(256) void scan_phase3(
    int* __restrict__ out1, const int* __restrict__ bsum, int n)
{
    int i = blockIdx.x * 256 + threadIdx.x;
    int add = (blockIdx.x > 0) ? bsum[blockIdx.x - 1] : 0;
    if (i < n) out1[i] += add;
    if (i == 0) out1[-1] = 0;     // offsets[0]
}

__global__ void scatter_edges(const int* __restrict__ src, const int* __restrict__ dst,
                              const int* __restrict__ offsets, int* __restrict__ cursor,
                              int* __restrict__ csr_src, int E) {
    int e = blockIdx.x * blockDim.x + threadIdx.x;
    if (e < E) {
        int d = dst[e];
        int pos = offsets[d] + atomicAdd(&cursor[d], 1);
        csr_src[pos] = src[e];
    }
}

// ---------------- W pre-transpose + bf16 hi/lo split ------------------------

__global__ void transpose_w_bf16(const float* __restrict__ W,
                                 ushort_t* __restrict__ Wt_hi,
                                 ushort_t* __restrict__ Wt_lo, int K, int Nw) {
    int idx = blockIdx.x * blockDim.x + threadIdx.x;
    if (idx >= K * Nw) return;
    int k = idx / Nw, n = idx - k * Nw;
    unsigned short h, l;
    bf16split(W[idx], h, l);
    Wt_hi[(size_t)n * K + k] = h;
    Wt_lo[(size_t)n * K + k] = l;
}

// ---------------- flat fp32 -> bf16 hi/lo split (float4 per thread) ---------

__global__ void split_f32(const float* __restrict__ x,
                          ushort_t* __restrict__ hi, ushort_t* __restrict__ lo, int n4) {
    int i = blockIdx.x * blockDim.x + threadIdx.x;
    if (i >= n4) return;
    float4 v = reinterpret_cast<const float4*>(x)[i];
    ushort4 h, l;
    bf16split(v.x, h.x, l.x);
    bf16split(v.y, h.y, l.y);
    bf16split(v.z, h.z, l.z);
    bf16split(v.w, h.w, l.w);
    reinterpret_cast<ushort4*>(hi)[i] = h;
    reinterpret_cast<ushort4*>(lo)[i] = l;
}

// ---------------- GEMM v3: pre-split A/B, BK=64, pure-copy staging ----------
// C = A[M,K] @ B[K,256]; BM=BN=64, 4 waves (2x2 quadrants, 2x2 16x16 frags).
// A as Ah/Al [M][K] bf16 bits; B as Bh/Bl [256][K] (pre-transposed).
// Epilogue: fp16 store + el/er partial dots -> atomicAdd (el/er pre-zeroed).

__global__ __launch_bounds__(256) void gemm_bf16split(
    const ushort_t* __restrict__ Ah, const ushort_t* __restrict__ Al,
    const ushort_t* __restrict__ Bh, const ushort_t* __restrict__ Bl,
    const float* __restrict__ alf, const float* __restrict__ arf,
    __half* __restrict__ feat16, float* __restrict__ el, float* __restrict__ er,
    int M, int K)
{
    const int LDT = 72;                 // 144B rows: 2-way bank alias (free)
    __shared__ ushort_t As_hi[64][LDT], As_lo[64][LDT];
    __shared__ ushort_t Bs_hi[64][LDT], Bs_lo[64][LDT];

    int tid = threadIdx.x, wv = tid >> 6, lane = tid & 63;
    int bm = blockIdx.x * 64, bn = blockIdx.y * 64;
    int wr = wv >> 1, wc = wv & 1;

    f32x4 acc[2][2] = {};

    int srow = tid >> 2;                // 0..63
    int sc0  = (tid & 3) * 16;          // 0,16,32,48 (+0/+8 per uint4)

    size_t abase = (size_t)min(bm + srow, M - 1) * K;
    size_t bbase = (size_t)(bn + srow) * K;

    int frow = lane & 15;
    int fkg  = (lane >> 4) * 8;

    for (int k0 = 0; k0 < K; k0 += 64) {
        #pragma unroll
        for (int j = 0; j < 2; ++j) {
            int c = sc0 + j * 8;
            *reinterpret_cast<uint4*>(&As_hi[srow][c]) =
                *reinterpret_cast<const uint4*>(&Ah[abase + k0 + c]);
            *reinterpret_cast<uint4*>(&As_lo[srow][c]) =
                *reinterpret_cast<const uint4*>(&Al[abase + k0 + c]);
            *reinterpret_cast<uint4*>(&Bs_hi[srow][c]) =
                *reinterpret_cast<const uint4*>(&Bh[bbase + k0 + c]);
            *reinterpret_cast<uint4*>(&Bs_lo[srow][c]) =
                *reinterpret_cast<const uint4*>(&Bl[bbase + k0 + c]);
        }
        __syncthreads();

        #pragma unroll
        for (int ks = 0; ks < 2; ++ks) {
            int kb = ks * 32 + fkg;
            bf16x8 ah[2], al_[2], bh[2], bl[2];
            #pragma unroll
            for (int i = 0; i < 2; ++i) {
                int r = wr * 32 + i * 16 + frow;
                ah[i]  = *reinterpret_cast<const bf16x8*>(&As_hi[r][kb]);
                al_[i] = *reinterpret_cast<const bf16x8*>(&As_lo[r][kb]);
            }
            #pragma unroll
            for (int j = 0; j < 2; ++j) {
                int r = wc * 32 + j * 16 + frow;
                bh[j] = *reinterpret_cast<const bf16x8*>(&Bs_hi[r][kb]);
                bl[j] = *reinterpret_cast<const bf16x8*>(&Bs_lo[r][kb]);
            }
            #pragma unroll
            for (int i = 0; i < 2; ++i)
                #pragma unroll
                for (int j = 0; j < 2; ++j) {
                    acc[i][j] = __builtin_amdgcn_mfma_f32_16x16x32_bf16(ah[i],  bh[j], acc[i][j], 0, 0, 0);
                    acc[i][j] = __builtin_amdgcn_mfma_f32_16x16x32_bf16(ah[i],  bl[j], acc[i][j], 0, 0, 0);
                    acc[i][j] = __builtin_amdgcn_mfma_f32_16x16x32_bf16(al_[i], bh[j], acc[i][j], 0, 0, 0);
                }
        }
        __syncthreads();
    }

    // ---- epilogue: C/D layout col=lane&15, row=(lane>>4)*4+reg ----
    int colbase = bn + wc * 32;
    int c0 = colbase + (lane & 15);
    int c1 = c0 + 16;
    float alw0 = alf[c0], alw1 = alf[c1];
    float arw0 = arf[c0], arw1 = arf[c1];
    int hH = colbase >> 7;
    int g4 = (lane >> 4) * 4;
    int sub = lane & 15;

    #pragma unroll
    for (int i = 0; i < 2; ++i) {
        int row0 = bm + wr * 32 + i * 16 + g4;
        #pragma unroll
        for (int r = 0; r < 4; ++r) {
            int row = row0 + r;
            if (row < M) {
                feat16[(size_t)row * 256 + c0] = __float2half(acc[i][0][r]);
                feat16[(size_t)row * 256 + c1] = __float2half(acc[i][1][r]);
            }
        }
        float pel[4], per_[4];
        #pragma unroll
        for (int r = 0; r < 4; ++r) {
            pel[r]  = acc[i][0][r] * alw0 + acc[i][1][r] * alw1;
            per_[r] = acc[i][0][r] * arw0 + acc[i][1][r] * arw1;
        }
        #pragma unroll
        for (int off = 1; off < 16; off <<= 1) {
            #pragma unroll
            for (int r = 0; r < 4; ++r) {
                pel[r]  += __shfl_xor(pel[r], off);
                per_[r] += __shfl_xor(per_[r], off);
            }
        }
        if (sub < 4) {
            int row = row0 + sub;
            float v = (sub == 0) ? pel[0] : (sub == 1) ? pel[1] : (sub == 2) ? pel[2] : pel[3];
            if (row < M) atomicAdd(&el[(size_t)row * 2 + hH], v);
        } else if (sub < 8) {
            int r = sub - 4;
            int row = row0 + r;
            float v = (r == 0) ? per_[0] : (r == 1) ? per_[1] : (r == 2) ? per_[2] : per_[3];
            if (row < M) atomicAdd(&er[(size_t)row * 2 + hH], v);
        }
    }
}

// ---------------- fused softmax + aggregation: one wave per node ------------
// If outHi != nullptr: also emit the output row as bf16 hi/lo (next GEMM's A).
// If W2 != nullptr: also emit feat2[n] = dot(out_row, W2) (fused gemv).

__global__ __launch_bounds__(256) void gat_fused_agg(
    const __half* __restrict__ feat16, const float* __restrict__ el, const float* __restrict__ er,
    const int* __restrict__ offsets, const int* __restrict__ csr_src,
    const float* __restrict__ bias, float* __restrict__ out, int N, int activate,
    const float* __restrict__ W2, float* __restrict__ feat2,
    ushort_t* __restrict__ outHi, ushort_t* __restrict__ outLo)
{
    int wv = threadIdx.x >> 6, lane = threadIdx.x & 63;
    int n = blockIdx.x * 4 + wv;
    if (n >= N) return;
    int hsel = lane >> 5;
    int d4 = (lane & 31) * 4 + hsel * 128;
    const char* fbase = (const char*)feat16 + (size_t)d4 * 2;
    int p0 = offsets[n], p1 = offsets[n + 1];

    float2 ern = *reinterpret_cast<const float2*>(er + 2 * (size_t)n);
    const float NEG_INF = -__builtin_inff();
    float m0 = NEG_INF, m1 = NEG_INF, s0 = 0.f, s1 = 0.f;
    float4 acc = make_float4(0.f, 0.f, 0.f, 0.f);

    for (int base = p0; base < p1; base += 32) {
        int cnt = min(32, p1 - base);
        int cl = lane & 31;
        bool active = cl < cnt;
        int src_v = csr_src[base + min(cl, cnt - 1)];
        float ex = NEG_INF, ey = NEG_INF;
        if (active) {
            float2 e2 = *reinterpret_cast<const float2*>(el + 2 * (size_t)src_v);
            ex = e2.x + ern.x; ey = e2.y + ern.y;
            ex = (ex >= 0.f) ? ex : NEG_ATTN * ex;
            ey = (ey >= 0.f) ? ey : NEG_ATTN * ey;
        }
        float mc0 = ex, mc1 = ey;
        #pragma unroll
        for (int off = 16; off; off >>= 1) {
            mc0 = fmaxf(mc0, __shfl_xor(mc0, off));
            mc1 = fmaxf(mc1, __shfl_xor(mc1, off));
        }
        float nm0 = fmaxf(m0, mc0), nm1 = fmaxf(m1, mc1);
        float sc0 = __expf(m0 - nm0), sc1 = __expf(m1 - nm1);
        float wx = active ? __expf(ex - nm0) : 0.f;
        float wy = active ? __expf(ey - nm1) : 0.f;
        float sw0 = wx, sw1 = wy;
        #pragma unroll
        for (int off = 16; off; off >>= 1) {
            sw0 += __shfl_xor(sw0, off);
            sw1 += __shfl_xor(sw1, off);
        }
        s0 = s0 * sc0 + sw0;
        s1 = s1 * sc1 + sw1;
        float scH = hsel ? sc1 : sc0;
        acc.x *= scH; acc.y *= scH; acc.z *= scH; acc.w *= scH;
        m0 = nm0; m1 = nm1;

        int c = 0;
        for (; c + 4 <= cnt; c += 4) {
            int   i0 = __shfl(src_v, c);
            int   i1 = __shfl(src_v, c + 1);
            int   i2 = __shfl(src_v, c + 2);
            int   i3 = __shfl(src_v, c + 3);
            float ax0 = __shfl(wx, c),     ay0 = __shfl(wy, c);
            float ax1 = __shfl(wx, c + 1), ay1 = __shfl(wy, c + 1);
            float ax2 = __shfl(wx, c + 2), ay2 = __shfl(wy, c + 2);
            float ax3 = __shfl(wx, c + 3), ay3 = __shfl(wy, c + 3);
            float a0 = hsel ? ay0 : ax0;
            float a1 = hsel ? ay1 : ax1;
            float a2 = hsel ? ay2 : ax2;
            float a3 = hsel ? ay3 : ax3;
            uint2 r0 = *reinterpret_cast<const uint2*>(fbase + (size_t)i0 * 512);
            uint2 r1 = *reinterpret_cast<const uint2*>(fbase + (size_t)i1 * 512);
            uint2 r2 = *reinterpret_cast<const uint2*>(fbase + (size_t)i2 * 512);
            uint2 r3 = *reinterpret_cast<const uint2*>(fbase + (size_t)i3 * 512);
            {
                float2 fa = __half22float2(*reinterpret_cast<const __half2*>(&r0.x));
                float2 fb = __half22float2(*reinterpret_cast<const __half2*>(&r0.y));
                acc.x = fmaf(a0, fa.x, acc.x); acc.y = fmaf(a0, fa.y, acc.y);
                acc.z = fmaf(a0, fb.x, acc.z); acc.w = fmaf(a0, fb.y, acc.w);
            }
            {
                float2 fa = __half22float2(*reinterpret_cast<const __half2*>(&r1.x));
                float2 fb = __half22float2(*reinterpret_cast<const __half2*>(&r1.y));
                acc.x = fmaf(a1, fa.x, acc.x); acc.y = fmaf(a1, fa.y, acc.y);
                acc.z = fmaf(a1, fb.x, acc.z); acc.w = fmaf(a1, fb.y, acc.w);
            }
            {
                float2 fa = __half22float2(*reinterpret_cast<const __half2*>(&r2.x));
                float2 fb = __half22float2(*reinterpret_cast<const __half2*>(&r2.y));
                acc.x = fmaf(a2, fa.x, acc.x); acc.y = fmaf(a2, fa.y, acc.y);
                acc.z = fmaf(a2, fb.x, acc.z); acc.w = fmaf(a2, fb.y, acc.w);
            }
            {
                float2 fa = __half22float2(*reinterpret_cast<const __half2*>(&r3.x));
                float2 fb = __half22float2(*reinterpret_cast<const __half2*>(&r3.y));
                acc.x = fmaf(a3, fa.x, acc.x); acc.y = fmaf(a3, fa.y, acc.y);
                acc.z = fmaf(a3, fb.x, acc.z); acc.w = fmaf(a3, fb.y, acc.w);
            }
        }
        for (; c < cnt; ++c) {
            int   i0 = __shfl(src_v, c);
            float ax0 = __shfl(wx, c), ay0 = __shfl(wy, c);
            float a0 = hsel ? ay0 : ax0;
            uint2 r0 = *reinterpret_cast<const uint2*>(fbase + (size_t)i0 * 512);
            float2 fa = __half22float2(*reinterpret_cast<const __half2*>(&r0.x));
            float2 fb = __half22float2(*reinterpret_cast<const __half2*>(&r0.y));
            acc.x = fmaf(a0, fa.x, acc.x); acc.y = fmaf(a0, fa.y, acc.y);
            acc.z = fmaf(a0, fb.x, acc.z); acc.w = fmaf(a0, fb.y, acc.w);
        }
    }

    float inv0 = (s0 > 0.f) ? 1.f / s0 : 0.f;
    float inv1 = (s1 > 0.f) ? 1.f / s1 : 0.f;
    float inv = hsel ? inv1 : inv0;
    float4 b4 = *reinterpret_cast<const float4*>(bias + d4);
    acc.x = fmaf(acc.x, inv, b4.x);
    acc.y = fmaf(acc.y, inv, b4.y);
    acc.z = fmaf(acc.z, inv, b4.z);
    acc.w = fmaf(acc.w, inv, b4.w);
    if (activate) {
        acc.x = (acc.x >= 0.f) ? acc.x : NEG_ACT * acc.x;
        acc.y = (acc.y >= 0.f) ? acc.y : NEG_ACT * acc.y;
        acc.z = (acc.z >= 0.f) ? acc.z : NEG_ACT * acc.z;
        acc.w = (acc.w >= 0.f) ? acc.w : NEG_ACT * acc.w;
    }
    *reinterpret_cast<float4*>(out + (size_t)n * 256 + d4) = acc;

    if (outHi != nullptr) {        // emit bf16 hi/lo copy (next GEMM's A)
        ushort4 h, l;
        bf16split(acc.x, h.x, l.x);
        bf16split(acc.y, h.y, l.y);
        bf16split(acc.z, h.z, l.z);
        bf16split(acc.w, h.w, l.w);
        *reinterpret_cast<ushort4*>(outHi + (size_t)n * 256 + d4) = h;
        *reinterpret_cast<ushort4*>(outLo + (size_t)n * 256 + d4) = l;
    }

    if (W2 != nullptr) {           // fused gemv: feat2[n] = dot(row, W2)
        float4 w4 = *reinterpret_cast<const float4*>(W2 + d4);
        float d = acc.x * w4.x + acc.y * w4.y + acc.z * w4.z + acc.w * w4.w;
        #pragma unroll
        for (int off = 32; off; off >>= 1) d += __shfl_xor(d, off);
        if (lane == 0) feat2[n] = d;
    }
}

// ---------------- layer 2: wave-per-node scalar softmax aggregate -----------

__global__ __launch_bounds__(256) void gat_aggregate2_wave(
    const float* __restrict__ feat2, const float* __restrict__ al2, const float* __restrict__ ar2,
    const float* __restrict__ b2, const int* __restrict__ offsets, const int* __restrict__ csr_src,
    float* __restrict__ out, int N)
{
    int wv = threadIdx.x >> 6, lane = threadIdx.x & 63;
    int n = blockIdx.x * 4 + wv;
    if (n >= N) return;
    float alv = al2[0], arv = ar2[0];
    float ern = feat2[n] * arv;
    int p0 = offsets[n], p1 = offsets[n + 1];
    const float NEG_INF = -__builtin_inff();
    float m = NEG_INF, s = 0.f, acc = 0.f;

    for (int base = p0; base < p1; base += 64) {
        bool active = (base + lane) < p1;
        int sn = active ? csr_src[base + lane] : 0;
        float f = active ? feat2[sn] : 0.f;
        float e = NEG_INF;
        if (active) {
            e = fmaf(f, alv, ern);
            e = (e >= 0.f) ? e : NEG_ATTN * e;
        }
        float mc = e;
        #pragma unroll
        for (int off = 32; off; off >>= 1) mc = fmaxf(mc, __shfl_xor(mc, off));
        float nm = fmaxf(m, mc);
        float sc = __expf(m - nm);
        float w = active ? __expf(e - nm) : 0.f;
        s   = s * sc + w;
        acc = acc * sc + w * f;
        m = nm;
    }
    #pragma unroll
    for (int off = 32; off; off >>= 1) {
        s   += __shfl_xor(s, off);
        acc += __shfl_xor(acc, off);
    }
    if (lane == 0) out[n] = ((s > 0.f) ? acc / s : 0.f) + b2[0];
}

// ---------------------------------------------------------------------------

extern "C" void kernel_launch(void* const* d_in, const int* in_sizes, int n_in,
                              void* d_out, int out_size, void* d_ws, size_t ws_size,
                              hipStream_t stream)
{
    const float* features = (const float*)d_in[0];
    const int*   src      = (const int*)d_in[1];
    const int*   dst      = (const int*)d_in[2];
    const float* W0  = (const float*)d_in[3];
    const float* al0 = (const float*)d_in[4];
    const float* ar0 = (const float*)d_in[5];
    const float* b0  = (const float*)d_in[6];
    const float* W1  = (const float*)d_in[7];
    const float* al1 = (const float*)d_in[8];
    const float* ar1 = (const float*)d_in[9];
    const float* b1  = (const float*)d_in[10];
    const float* W2  = (const float*)d_in[11];
    const float* al2 = (const float*)d_in[12];
    const float* ar2 = (const float*)d_in[13];
    const float* b2  = (const float*)d_in[14];

    const int IN = 128, HD = 256;
    const int N = in_sizes[0] / IN;
    const int E = in_sizes[1];
    const int NB = (N + 255) / 256;          // scan blocks

    float* out_final = (float*)d_out;        // [N]
    float* h2        = (float*)d_out + N;    // [N,256] (returned h; layer-0 hidden)

    char* ws = (char*)d_ws;
    size_t off = 0;
    auto alloc = [&](size_t bytes) { void* p = ws + off; off += (bytes + 255) & ~255ULL; return p; };
    __half*   featH  = (__half*)alloc((size_t)N * HD * 2);
    ushort_t* Fh     = (ushort_t*)alloc((size_t)N * IN * 2);
    ushort_t* Fl     = (ushort_t*)alloc((size_t)N * IN * 2);
    ushort_t* H1h    = (ushort_t*)alloc((size_t)N * HD * 2);
    ushort_t* H1l    = (ushort_t*)alloc((size_t)N * HD * 2);
    float*    el     = (float*)alloc((size_t)N * 2 * 4);
    float*    er     = (float*)alloc((size_t)N * 2 * 4);
    float*    feat2  = (float*)alloc((size_t)N * 4);
    int*      counts = (int*)alloc((size_t)N * 4);
    int*      cursor = (int*)alloc((size_t)N * 4);
    int*      offs   = (int*)alloc((size_t)(N + 1) * 4);
    int*      bsum   = (int*)alloc((size_t)NB * 4);
    int*      csr_src = (int*)alloc((size_t)E * 4);
    ushort_t* Wt0h = (ushort_t*)alloc((size_t)IN * HD * 2);
    ushort_t* Wt0l = (ushort_t*)alloc((size_t)IN * HD * 2);
    ushort_t* Wt1h = (ushort_t*)alloc((size_t)HD * HD * 2);
    ushort_t* Wt1l = (ushort_t*)alloc((size_t)HD * HD * 2);

    hipMemsetAsync(counts, 0, (size_t)N * 4, stream);
    hipMemsetAsync(cursor, 0, (size_t)N * 4, stream);

    transpose_w_bf16<<<(IN * HD + 255) / 256, 256, 0, stream>>>(W0, Wt0h, Wt0l, IN, HD);
    transpose_w_bf16<<<(HD * HD + 255) / 256, 256, 0, stream>>>(W1, Wt1h, Wt1l, HD, HD);
    split_f32<<<((N * IN / 4) + 255) / 256, 256, 0, stream>>>(features, Fh, Fl, N * IN / 4);

    count_edges<<<(E + 255) / 256, 256, 0, stream>>>(dst, counts, E);
    scan_phase1<<<NB, 256, 0, stream>>>(counts, offs + 1, bsum, N);
    scan_phase2<<<1, 256, 0, stream>>>(bsum, NB);
    scan_phase3<<<NB, 256, 0, stream>>>(offs + 1, bsum, N);
    scatter_edges<<<(E + 255) / 256, 256, 0, stream>>>(src, dst, offs, cursor, csr_src, E);

    dim3 gemm_grid((N + 63) / 64, HD / 64);

    // layer 0 (fp16 features + el/er from GEMM; agg emits h1 bf16 hi/lo)
    hipMemsetAsync(el, 0, (size_t)N * 2 * 4, stream);
    hipMemsetAsync(er, 0, (size_t)N * 2 * 4, stream);
    gemm_bf16split<<<gemm_grid, 256, 0, stream>>>(Fh, Fl, Wt0h, Wt0l, al0, ar0,
                                                  featH, el, er, N, IN);
    gat_fused_agg<<<(N + 3) / 4, 256, 0, stream>>>(featH, el, er, offs, csr_src, b0,
                                                   h2, N, 1, nullptr, nullptr, H1h, H1l);

    // layer 1 (pre-split h1 -> featH/el/er; agg writes final h AND feat2)
    hipMemsetAsync(el, 0, (size_t)N * 2 * 4, stream);
    hipMemsetAsync(er, 0, (size_t)N * 2 * 4, stream);
    gemm_bf16split<<<gemm_grid, 256, 0, stream>>>(H1h, H1l, Wt1h, Wt1l, al1, ar1,
                                                  featH, el, er, N, HD);
    gat_fused_agg<<<(N + 3) / 4, 256, 0, stream>>>(featH, el, er, offs, csr_src, b1,
                                                   h2, N, 1, W2, feat2, nullptr, nullptr);

    // layer 2 (scalar head, wave-per-node)
    gat_aggregate2_wave<<<(N + 3) / 4, 256, 0, stream>>>(feat2, al2, ar2, b2, offs,
                                                         csr_src, out_final, N);
}

// Round 8
// 405.925 us; speedup vs baseline: 1.7431x; 1.0710x over previous
//
#include <hip/hip_runtime.h>
#include <hip/hip_fp16.h>
#include <math.h>

// ---------------------------------------------------------------------------
// GAT network: 3 layers. N=50000 nodes, E=800000 edges, IN=128, H=2, D=128.
// CSR-by-dst once per call (parallel 3-kernel scan). Per layer:
//   gemm_bn256: bf16 split-MFMA GEMM (pre-split hi/lo A and B), BN=256 ->
//     each block computes full 256-wide rows; epilogue writes fp16 features
//     and computes el/er via in-block LDS reduction (no atomics/memsets).
//   gat_fused_agg: one-wave-per-node exact segment softmax + fp16 weighted
//     aggregation; layer-0 emits ONLY bf16 hi/lo h1 (fp32 store dead);
//     layer-1 writes final h and feat2 = h . W2 (fused gemv).
// Final layer: wave-per-node lane-parallel scalar softmax aggregate.
// ---------------------------------------------------------------------------

#define NEG_ATTN 0.2f
#define NEG_ACT  0.01f

typedef short bf16x8 __attribute__((ext_vector_type(8)));
typedef float f32x4  __attribute__((ext_vector_type(4)));
typedef unsigned short ushort_t;

__device__ inline void bf16split(float x, unsigned short& h, unsigned short& l) {
    unsigned b = __float_as_uint(x);
    h = (unsigned short)(b >> 16);
    float hf = __uint_as_float(b & 0xFFFF0000u);
    l = (unsigned short)(__float_as_uint(x - hf) >> 16);
}

// ---------------- CSR build ----------------

__global__ void count_edges(const int* __restrict__ dst, int* __restrict__ counts, int E) {
    int e = blockIdx.x * blockDim.x + threadIdx.x;
    if (e < E) atomicAdd(&counts[dst[e]], 1);
}

__global__ __launch_bounds__(256) void scan_phase1(
    const int* __restrict__ in, int* __restrict__ out1 /* = offsets+1 */,
    int* __restrict__ bsum, int n)
{
    __shared__ int wsum[4];
    int i = blockIdx.x * 256 + threadIdx.x;
    int lane = threadIdx.x & 63, wv = threadIdx.x >> 6;
    int v = (i < n) ? in[i] : 0;
    int x = v;
    #pragma unroll
    for (int off = 1; off < 64; off <<= 1) {
        int y = __shfl_up(x, off);
        if (lane >= off) x += y;
    }
    if (lane == 63) wsum[wv] = x;
    __syncthreads();
    int add = 0;
    for (int w = 0; w < wv; ++w) add += wsum[w];
    x += add;
    if (i < n) out1[i] = x;
    if (threadIdx.x == 255) bsum[blockIdx.x] = x;
}

__global__ __launch_bounds__(256) void scan_phase2(int* __restrict__ bsum, int nb) {
    __shared__ int wsum[4];
    int t = threadIdx.x;
    int lane = t & 63, wv = t >> 6;
    int x = (t < nb) ? bsum[t] : 0;
    #pragma unroll
    for (int off = 1; off < 64; off <<= 1) {
        int y = __shfl_up(x, off);
        if (lane >= off) x += y;
    }
    if (lane == 63) wsum[wv] = x;
    __syncthreads();
    int add = 0;
    for (int w = 0; w < wv; ++w) add += wsum[w];
    x += add;
    if (t < nb) bsum[t] = x;
}

__global__ __launch_bounds__(256) void scan_phase3(
    int* __restrict__ out1, const int* __restrict__ bsum, int n)
{
    int i = blockIdx.x * 256 + threadIdx.x;
    int add = (blockIdx.x > 0) ? bsum[blockIdx.x - 1] : 0;
    if (i < n) out1[i] += add;
    if (i == 0) out1[-1] = 0;     // offsets[0]
}

__global__ void scatter_edges(const int* __restrict__ src, const int* __restrict__ dst,
                              const int* __restrict__ offsets, int* __restrict__ cursor,
                              int* __restrict__ csr_src, int E) {
    int e = blockIdx.x * blockDim.x + threadIdx.x;
    if (e < E) {
        int d = dst[e];
        int pos = offsets[d] + atomicAdd(&cursor[d], 1);
        csr_src[pos] = src[e];
    }
}

// ---------------- W pre-transpose + bf16 hi/lo split ------------------------

__global__ void transpose_w_bf16(const float* __restrict__ W,
                                 ushort_t* __restrict__ Wt_hi,
                                 ushort_t* __restrict__ Wt_lo, int K, int Nw) {
    int idx = blockIdx.x * blockDim.x + threadIdx.x;
    if (idx >= K * Nw) return;
    int k = idx / Nw, n = idx - k * Nw;
    unsigned short h, l;
    bf16split(W[idx], h, l);
    Wt_hi[(size_t)n * K + k] = h;
    Wt_lo[(size_t)n * K + k] = l;
}

__global__ void split_f32(const float* __restrict__ x,
                          ushort_t* __restrict__ hi, ushort_t* __restrict__ lo, int n4) {
    int i = blockIdx.x * blockDim.x + threadIdx.x;
    if (i >= n4) return;
    float4 v = reinterpret_cast<const float4*>(x)[i];
    ushort4 h, l;
    bf16split(v.x, h.x, l.x);
    bf16split(v.y, h.y, l.y);
    bf16split(v.z, h.z, l.z);
    bf16split(v.w, h.w, l.w);
    reinterpret_cast<ushort4*>(hi)[i] = h;
    reinterpret_cast<ushort4*>(lo)[i] = l;
}

// ---------------- GEMM v4: BN=256 full-row blocks ---------------------------
// C = A[M,K] @ B[K,256]; BM=64, BN=256, BK=32. 512 threads = 8 waves (2x4):
// wave (wr,wc) -> rows wr*32..+32, cols wc*64..+64; 2x4 16x16 frags/wave.
// A as Ah/Al [M][K]; B as Bh/Bl [256][K] (pre-transposed). 3-MFMA hi/lo.
// Epilogue: fp16 store + el/er via in-block LDS reduce (no atomics).

__global__ __launch_bounds__(512) void gemm_bn256(
    const ushort_t* __restrict__ Ah, const ushort_t* __restrict__ Al,
    const ushort_t* __restrict__ Bh, const ushort_t* __restrict__ Bl,
    const float* __restrict__ alf, const float* __restrict__ arf,
    __half* __restrict__ feat16, float* __restrict__ el, float* __restrict__ er,
    int M, int K)
{
    const int LDT = 40;                 // 32 + 8 pad (80B rows, 16B-aligned)
    __shared__ ushort_t As_hi[64][LDT], As_lo[64][LDT];
    __shared__ ushort_t Bs_hi[256][LDT], Bs_lo[256][LDT];
    __shared__ float part_el[64][4], part_er[64][4];

    int tid = threadIdx.x, wv = tid >> 6, lane = tid & 63;
    int bm = blockIdx.x * 64;
    int wr = wv >> 2, wc = wv & 3;

    f32x4 acc[2][4] = {};

    // staging maps
    int t2   = tid & 255;
    int arow = t2 >> 2;                  // 0..63
    int akg  = (t2 & 3) * 8;             // 0,8,16,24
    size_t abase = (size_t)min(bm + arow, M - 1) * K + akg;
    int half = tid >> 8;                 // 0: A_hi, 1: A_lo

    int frow = lane & 15;
    int fkg  = (lane >> 4) * 8;

    for (int k0 = 0; k0 < K; k0 += 32) {
        // A: threads 0..255 stage hi, 256..511 stage lo
        if (half == 0)
            *reinterpret_cast<uint4*>(&As_hi[arow][akg]) =
                *reinterpret_cast<const uint4*>(&Ah[abase + k0]);
        else
            *reinterpret_cast<uint4*>(&As_lo[arow][akg]) =
                *reinterpret_cast<const uint4*>(&Al[abase + k0]);
        // B: 1024 uint4 per array; 2 loads/thread each
        #pragma unroll
        for (int j = 0; j < 2; ++j) {
            int L = tid + 512 * j;
            int brow = L >> 2, bkg = (L & 3) * 8;
            size_t g = (size_t)brow * K + k0 + bkg;
            *reinterpret_cast<uint4*>(&Bs_hi[brow][bkg]) =
                *reinterpret_cast<const uint4*>(&Bh[g]);
            *reinterpret_cast<uint4*>(&Bs_lo[brow][bkg]) =
                *reinterpret_cast<const uint4*>(&Bl[g]);
        }
        __syncthreads();

        bf16x8 ah[2], al_[2], bh[4], bl[4];
        #pragma unroll
        for (int i = 0; i < 2; ++i) {
            int r = wr * 32 + i * 16 + frow;
            ah[i]  = *reinterpret_cast<const bf16x8*>(&As_hi[r][fkg]);
            al_[i] = *reinterpret_cast<const bf16x8*>(&As_lo[r][fkg]);
        }
        #pragma unroll
        for (int j = 0; j < 4; ++j) {
            int c = wc * 64 + j * 16 + frow;
            bh[j] = *reinterpret_cast<const bf16x8*>(&Bs_hi[c][fkg]);
            bl[j] = *reinterpret_cast<const bf16x8*>(&Bs_lo[c][fkg]);
        }
        #pragma unroll
        for (int i = 0; i < 2; ++i)
            #pragma unroll
            for (int j = 0; j < 4; ++j) {
                acc[i][j] = __builtin_amdgcn_mfma_f32_16x16x32_bf16(ah[i],  bh[j], acc[i][j], 0, 0, 0);
                acc[i][j] = __builtin_amdgcn_mfma_f32_16x16x32_bf16(ah[i],  bl[j], acc[i][j], 0, 0, 0);
                acc[i][j] = __builtin_amdgcn_mfma_f32_16x16x32_bf16(al_[i], bh[j], acc[i][j], 0, 0, 0);
            }
        __syncthreads();
    }

    // ---- epilogue. C/D layout: col=lane&15, row=(lane>>4)*4+reg ----
    int g4 = (lane >> 4) * 4;
    float alw[4], arw[4];
    #pragma unroll
    for (int j = 0; j < 4; ++j) {
        int c = wc * 64 + j * 16 + frow;
        alw[j] = alf[c];
        arw[j] = arf[c];
    }

    #pragma unroll
    for (int i = 0; i < 2; ++i) {
        int row0 = bm + wr * 32 + i * 16 + g4;
        // fp16 stores (cols wc*64 + j*16 + frow)
        #pragma unroll
        for (int r = 0; r < 4; ++r) {
            int row = row0 + r;
            if (row < M) {
                #pragma unroll
                for (int j = 0; j < 4; ++j)
                    feat16[(size_t)row * 256 + wc * 64 + j * 16 + frow] =
                        __float2half(acc[i][j][r]);
            }
        }
        // partial el/er over this wave's 64 cols
        float pel[4], per_[4];
        #pragma unroll
        for (int r = 0; r < 4; ++r) {
            float pe = 0.f, pr = 0.f;
            #pragma unroll
            for (int j = 0; j < 4; ++j) {
                pe = fmaf(acc[i][j][r], alw[j], pe);
                pr = fmaf(acc[i][j][r], arw[j], pr);
            }
            pel[r] = pe; per_[r] = pr;
        }
        #pragma unroll
        for (int off = 1; off < 16; off <<= 1) {
            #pragma unroll
            for (int r = 0; r < 4; ++r) {
                pel[r]  += __shfl_xor(pel[r], off);
                per_[r] += __shfl_xor(per_[r], off);
            }
        }
        if (frow == 0) {                    // lanes 0,16,32,48 (one per g4 group)
            int lrow = wr * 32 + i * 16 + g4;
            #pragma unroll
            for (int r = 0; r < 4; ++r) {
                part_el[lrow + r][wc] = pel[r];
                part_er[lrow + r][wc] = per_[r];
            }
        }
    }
    __syncthreads();

    // combine: head0 = wc 0+1, head1 = wc 2+3.  256 values by tid<256.
    if (tid < 256) {
        int row = tid >> 2, which = tid & 3;
        int grow = bm + row;
        if (grow < M) {
            float v;
            if (which == 0)      v = part_el[row][0] + part_el[row][1];
            else if (which == 1) v = part_el[row][2] + part_el[row][3];
            else if (which == 2) v = part_er[row][0] + part_er[row][1];
            else                 v = part_er[row][2] + part_er[row][3];
            if (which < 2) el[(size_t)grow * 2 + which] = v;
            else           er[(size_t)grow * 2 + (which - 2)] = v;
        }
    }
}

// ---------------- fused softmax + aggregation: one wave per node ------------
// out == nullptr: skip the fp32 store (layer-0: only hi/lo copy is consumed).
// outHi != nullptr: emit bf16 hi/lo copy. W2 != nullptr: feat2[n] = row.W2.

__global__ __launch_bounds__(256) void gat_fused_agg(
    const __half* __restrict__ feat16, const float* __restrict__ el, const float* __restrict__ er,
    const int* __restrict__ offsets, const int* __restrict__ csr_src,
    const float* __restrict__ bias, float* __restrict__ out, int N, int activate,
    const float* __restrict__ W2, float* __restrict__ feat2,
    ushort_t* __restrict__ outHi, ushort_t* __restrict__ outLo)
{
    int wv = threadIdx.x >> 6, lane = threadIdx.x & 63;
    int n = blockIdx.x * 4 + wv;
    if (n >= N) return;
    int hsel = lane >> 5;
    int d4 = (lane & 31) * 4 + hsel * 128;
    const char* fbase = (const char*)feat16 + (size_t)d4 * 2;
    int p0 = offsets[n], p1 = offsets[n + 1];

    float2 ern = *reinterpret_cast<const float2*>(er + 2 * (size_t)n);
    const float NEG_INF = -__builtin_inff();
    float m0 = NEG_INF, m1 = NEG_INF, s0 = 0.f, s1 = 0.f;
    float4 acc = make_float4(0.f, 0.f, 0.f, 0.f);

    for (int base = p0; base < p1; base += 32) {
        int cnt = min(32, p1 - base);
        int cl = lane & 31;
        bool active = cl < cnt;
        int src_v = csr_src[base + min(cl, cnt - 1)];
        float ex = NEG_INF, ey = NEG_INF;
        if (active) {
            float2 e2 = *reinterpret_cast<const float2*>(el + 2 * (size_t)src_v);
            ex = e2.x + ern.x; ey = e2.y + ern.y;
            ex = (ex >= 0.f) ? ex : NEG_ATTN * ex;
            ey = (ey >= 0.f) ? ey : NEG_ATTN * ey;
        }
        float mc0 = ex, mc1 = ey;
        #pragma unroll
        for (int off = 16; off; off >>= 1) {
            mc0 = fmaxf(mc0, __shfl_xor(mc0, off));
            mc1 = fmaxf(mc1, __shfl_xor(mc1, off));
        }
        float nm0 = fmaxf(m0, mc0), nm1 = fmaxf(m1, mc1);
        float sc0 = __expf(m0 - nm0), sc1 = __expf(m1 - nm1);
        float wx = active ? __expf(ex - nm0) : 0.f;
        float wy = active ? __expf(ey - nm1) : 0.f;
        float sw0 = wx, sw1 = wy;
        #pragma unroll
        for (int off = 16; off; off >>= 1) {
            sw0 += __shfl_xor(sw0, off);
            sw1 += __shfl_xor(sw1, off);
        }
        s0 = s0 * sc0 + sw0;
        s1 = s1 * sc1 + sw1;
        float scH = hsel ? sc1 : sc0;
        acc.x *= scH; acc.y *= scH; acc.z *= scH; acc.w *= scH;
        m0 = nm0; m1 = nm1;

        int c = 0;
        for (; c + 4 <= cnt; c += 4) {
            int   i0 = __shfl(src_v, c);
            int   i1 = __shfl(src_v, c + 1);
            int   i2 = __shfl(src_v, c + 2);
            int   i3 = __shfl(src_v, c + 3);
            float ax0 = __shfl(wx, c),     ay0 = __shfl(wy, c);
            float ax1 = __shfl(wx, c + 1), ay1 = __shfl(wy, c + 1);
            float ax2 = __shfl(wx, c + 2), ay2 = __shfl(wy, c + 2);
            float ax3 = __shfl(wx, c + 3), ay3 = __shfl(wy, c + 3);
            float a0 = hsel ? ay0 : ax0;
            float a1 = hsel ? ay1 : ax1;
            float a2 = hsel ? ay2 : ax2;
            float a3 = hsel ? ay3 : ax3;
            uint2 r0 = *reinterpret_cast<const uint2*>(fbase + (size_t)i0 * 512);
            uint2 r1 = *reinterpret_cast<const uint2*>(fbase + (size_t)i1 * 512);
            uint2 r2 = *reinterpret_cast<const uint2*>(fbase + (size_t)i2 * 512);
            uint2 r3 = *reinterpret_cast<const uint2*>(fbase + (size_t)i3 * 512);
            {
                float2 fa = __half22float2(*reinterpret_cast<const __half2*>(&r0.x));
                float2 fb = __half22float2(*reinterpret_cast<const __half2*>(&r0.y));
                acc.x = fmaf(a0, fa.x, acc.x); acc.y = fmaf(a0, fa.y, acc.y);
                acc.z = fmaf(a0, fb.x, acc.z); acc.w = fmaf(a0, fb.y, acc.w);
            }
            {
                float2 fa = __half22float2(*reinterpret_cast<const __half2*>(&r1.x));
                float2 fb = __half22float2(*reinterpret_cast<const __half2*>(&r1.y));
                acc.x = fmaf(a1, fa.x, acc.x); acc.y = fmaf(a1, fa.y, acc.y);
                acc.z = fmaf(a1, fb.x, acc.z); acc.w = fmaf(a1, fb.y, acc.w);
            }
            {
                float2 fa = __half22float2(*reinterpret_cast<const __half2*>(&r2.x));
                float2 fb = __half22float2(*reinterpret_cast<const __half2*>(&r2.y));
                acc.x = fmaf(a2, fa.x, acc.x); acc.y = fmaf(a2, fa.y, acc.y);
                acc.z = fmaf(a2, fb.x, acc.z); acc.w = fmaf(a2, fb.y, acc.w);
            }
            {
                float2 fa = __half22float2(*reinterpret_cast<const __half2*>(&r3.x));
                float2 fb = __half22float2(*reinterpret_cast<const __half2*>(&r3.y));
                acc.x = fmaf(a3, fa.x, acc.x); acc.y = fmaf(a3, fa.y, acc.y);
                acc.z = fmaf(a3, fb.x, acc.z); acc.w = fmaf(a3, fb.y, acc.w);
            }
        }
        for (; c < cnt; ++c) {
            int   i0 = __shfl(src_v, c);
            float ax0 = __shfl(wx, c), ay0 = __shfl(wy, c);
            float a0 = hsel ? ay0 : ax0;
            uint2 r0 = *reinterpret_cast<const uint2*>(fbase + (size_t)i0 * 512);
            float2 fa = __half22float2(*reinterpret_cast<const __half2*>(&r0.x));
            float2 fb = __half22float2(*reinterpret_cast<const __half2*>(&r0.y));
            acc.x = fmaf(a0, fa.x, acc.x); acc.y = fmaf(a0, fa.y, acc.y);
            acc.z = fmaf(a0, fb.x, acc.z); acc.w = fmaf(a0, fb.y, acc.w);
        }
    }

    float inv0 = (s0 > 0.f) ? 1.f / s0 : 0.f;
    float inv1 = (s1 > 0.f) ? 1.f / s1 : 0.f;
    float inv = hsel ? inv1 : inv0;
    float4 b4 = *reinterpret_cast<const float4*>(bias + d4);
    acc.x = fmaf(acc.x, inv, b4.x);
    acc.y = fmaf(acc.y, inv, b4.y);
    acc.z = fmaf(acc.z, inv, b4.z);
    acc.w = fmaf(acc.w, inv, b4.w);
    if (activate) {
        acc.x = (acc.x >= 0.f) ? acc.x : NEG_ACT * acc.x;
        acc.y = (acc.y >= 0.f) ? acc.y : NEG_ACT * acc.y;
        acc.z = (acc.z >= 0.f) ? acc.z : NEG_ACT * acc.z;
        acc.w = (acc.w >= 0.f) ? acc.w : NEG_ACT * acc.w;
    }
    if (out != nullptr)
        *reinterpret_cast<float4*>(out + (size_t)n * 256 + d4) = acc;

    if (outHi != nullptr) {        // emit bf16 hi/lo copy (next GEMM's A)
        ushort4 h, l;
        bf16split(acc.x, h.x, l.x);
        bf16split(acc.y, h.y, l.y);
        bf16split(acc.z, h.z, l.z);
        bf16split(acc.w, h.w, l.w);
        *reinterpret_cast<ushort4*>(outHi + (size_t)n * 256 + d4) = h;
        *reinterpret_cast<ushort4*>(outLo + (size_t)n * 256 + d4) = l;
    }

    if (W2 != nullptr) {           // fused gemv: feat2[n] = dot(row, W2)
        float4 w4 = *reinterpret_cast<const float4*>(W2 + d4);
        float d = acc.x * w4.x + acc.y * w4.y + acc.z * w4.z + acc.w * w4.w;
        #pragma unroll
        for (int off = 32; off; off >>= 1) d += __shfl_xor(d, off);
        if (lane == 0) feat2[n] = d;
    }
}

// ---------------- layer 2: wave-per-node scalar softmax aggregate -----------

__global__ __launch_bounds__(256) void gat_aggregate2_wave(
    const float* __restrict__ feat2, const float* __restrict__ al2, const float* __restrict__ ar2,
    const float* __restrict__ b2, const int* __restrict__ offsets, const int* __restrict__ csr_src,
    float* __restrict__ out, int N)
{
    int wv = threadIdx.x >> 6, lane = threadIdx.x & 63;
    int n = blockIdx.x * 4 + wv;
    if (n >= N) return;
    float alv = al2[0], arv = ar2[0];
    float ern = feat2[n] * arv;
    int p0 = offsets[n], p1 = offsets[n + 1];
    const float NEG_INF = -__builtin_inff();
    float m = NEG_INF, s = 0.f, acc = 0.f;

    for (int base = p0; base < p1; base += 64) {
        bool active = (base + lane) < p1;
        int sn = active ? csr_src[base + lane] : 0;
        float f = active ? feat2[sn] : 0.f;
        float e = NEG_INF;
        if (active) {
            e = fmaf(f, alv, ern);
            e = (e >= 0.f) ? e : NEG_ATTN * e;
        }
        float mc = e;
        #pragma unroll
        for (int off = 32; off; off >>= 1) mc = fmaxf(mc, __shfl_xor(mc, off));
        float nm = fmaxf(m, mc);
        float sc = __expf(m - nm);
        float w = active ? __expf(e - nm) : 0.f;
        s   = s * sc + w;
        acc = acc * sc + w * f;
        m = nm;
    }
    #pragma unroll
    for (int off = 32; off; off >>= 1) {
        s   += __shfl_xor(s, off);
        acc += __shfl_xor(acc, off);
    }
    if (lane == 0) out[n] = ((s > 0.f) ? acc / s : 0.f) + b2[0];
}

// ---------------------------------------------------------------------------

extern "C" void kernel_launch(void* const* d_in, const int* in_sizes, int n_in,
                              void* d_out, int out_size, void* d_ws, size_t ws_size,
                              hipStream_t stream)
{
    const float* features = (const float*)d_in[0];
    const int*   src      = (const int*)d_in[1];
    const int*   dst      = (const int*)d_in[2];
    const float* W0  = (const float*)d_in[3];
    const float* al0 = (const float*)d_in[4];
    const float* ar0 = (const float*)d_in[5];
    const float* b0  = (const float*)d_in[6];
    const float* W1  = (const float*)d_in[7];
    const float* al1 = (const float*)d_in[8];
    const float* ar1 = (const float*)d_in[9];
    const float* b1  = (const float*)d_in[10];
    const float* W2  = (const float*)d_in[11];
    const float* al2 = (const float*)d_in[12];
    const float* ar2 = (const float*)d_in[13];
    const float* b2  = (const float*)d_in[14];

    const int IN = 128, HD = 256;
    const int N = in_sizes[0] / IN;
    const int E = in_sizes[1];
    const int NB = (N + 255) / 256;

    float* out_final = (float*)d_out;        // [N]
    float* h2        = (float*)d_out + N;    // [N,256] (returned h)

    char* ws = (char*)d_ws;
    size_t off = 0;
    auto alloc = [&](size_t bytes) { void* p = ws + off; off += (bytes + 255) & ~255ULL; return p; };
    __half*   featH  = (__half*)alloc((size_t)N * HD * 2);
    ushort_t* Fh     = (ushort_t*)alloc((size_t)N * IN * 2);
    ushort_t* Fl     = (ushort_t*)alloc((size_t)N * IN * 2);
    ushort_t* H1h    = (ushort_t*)alloc((size_t)N * HD * 2);
    ushort_t* H1l    = (ushort_t*)alloc((size_t)N * HD * 2);
    float*    el     = (float*)alloc((size_t)N * 2 * 4);
    float*    er     = (float*)alloc((size_t)N * 2 * 4);
    float*    feat2  = (float*)alloc((size_t)N * 4);
    int*      counts = (int*)alloc((size_t)N * 4);
    int*      cursor = (int*)alloc((size_t)N * 4);
    int*      offs   = (int*)alloc((size_t)(N + 1) * 4);
    int*      bsum   = (int*)alloc((size_t)NB * 4);
    int*      csr_src = (int*)alloc((size_t)E * 4);
    ushort_t* Wt0h = (ushort_t*)alloc((size_t)IN * HD * 2);
    ushort_t* Wt0l = (ushort_t*)alloc((size_t)IN * HD * 2);
    ushort_t* Wt1h = (ushort_t*)alloc((size_t)HD * HD * 2);
    ushort_t* Wt1l = (ushort_t*)alloc((size_t)HD * HD * 2);

    hipMemsetAsync(counts, 0, (size_t)N * 4, stream);
    hipMemsetAsync(cursor, 0, (size_t)N * 4, stream);

    transpose_w_bf16<<<(IN * HD + 255) / 256, 256, 0, stream>>>(W0, Wt0h, Wt0l, IN, HD);
    transpose_w_bf16<<<(HD * HD + 255) / 256, 256, 0, stream>>>(W1, Wt1h, Wt1l, HD, HD);
    split_f32<<<((N * IN / 4) + 255) / 256, 256, 0, stream>>>(features, Fh, Fl, N * IN / 4);

    count_edges<<<(E + 255) / 256, 256, 0, stream>>>(dst, counts, E);
    scan_phase1<<<NB, 256, 0, stream>>>(counts, offs + 1, bsum, N);
    scan_phase2<<<1, 256, 0, stream>>>(bsum, NB);
    scan_phase3<<<NB, 256, 0, stream>>>(offs + 1, bsum, N);
    scatter_edges<<<(E + 255) / 256, 256, 0, stream>>>(src, dst, offs, cursor, csr_src, E);

    int gblocks = (N + 63) / 64;

    // layer 0: GEMM -> featH/el/er; agg emits ONLY h1 bf16 hi/lo
    gemm_bn256<<<gblocks, 512, 0, stream>>>(Fh, Fl, Wt0h, Wt0l, al0, ar0,
                                            featH, el, er, N, IN);
    gat_fused_agg<<<(N + 3) / 4, 256, 0, stream>>>(featH, el, er, offs, csr_src, b0,
                                                   nullptr, N, 1, nullptr, nullptr, H1h, H1l);

    // layer 1: GEMM -> featH/el/er; agg writes final h AND feat2 = h.W2
    gemm_bn256<<<gblocks, 512, 0, stream>>>(H1h, H1l, Wt1h, Wt1l, al1, ar1,
                                            featH, el, er, N, HD);
    gat_fused_agg<<<(N + 3) / 4, 256, 0, stream>>>(featH, el, er, offs, csr_src, b1,
                                                   h2, N, 1, W2, feat2, nullptr, nullptr);

    // layer 2 (scalar head, wave-per-node)
    gat_aggregate2_wave<<<(N + 3) / 4, 256, 0, stream>>>(feat2, al2, ar2, b2, offs,
                                                         csr_src, out_final, N);
}